// Round 2
// baseline (695004.004 us; speedup 1.0000x reference)
//
#include <hip/hip_runtime.h>
#include <hip/hip_bf16.h>

// ---------------- model dims ----------------
#define V_   128
#define L_   300
#define EU_  256
#define GU_  1024    // 4*EU
#define NSTEP (299*128)   // 38272 decoder steps

typedef float v2f __attribute__((ext_vector_type(2)));

__device__ __forceinline__ v2f mk2(float x, float y) { v2f r; r.x = x; r.y = y; return r; }
__device__ __forceinline__ float sigmoidf_(float x) { return 1.f / (1.f + __expf(-x)); }
__device__ __forceinline__ float tanhf_(float x) { return 2.f / (1.f + __expf(-2.f * x)) - 1.f; }

// z[j] = dot(h[0:256], Wcol_j) with Wcol in registers (v2f pairs), h broadcast from LDS
__device__ __forceinline__ float dot256(const v2f* wreg, const float4* h4) {
    v2f a0 = mk2(0.f, 0.f), a1 = mk2(0.f, 0.f), a2 = mk2(0.f, 0.f), a3 = mk2(0.f, 0.f);
#pragma unroll
    for (int q = 0; q < 64; q += 2) {
        float4 ha = h4[q];
        a0 += mk2(ha.x, ha.y) * wreg[2 * q];
        a1 += mk2(ha.z, ha.w) * wreg[2 * q + 1];
        float4 hb = h4[q + 1];
        a2 += mk2(hb.x, hb.y) * wreg[2 * q + 2];
        a3 += mk2(hb.z, hb.w) * wreg[2 * q + 3];
    }
    v2f s = (a0 + a1) + (a2 + a3);
    return s.x + s.y;
}

// ---------------- tok extraction ----------------
__global__ void tok_kernel(const float* __restrict__ din, int* __restrict__ tok) {
    int l = blockIdx.x * 64 + threadIdx.x;
    if (l >= 299) return;
    int t = 0;
    for (int v = 0; v < 128; ++v)
        if (din[l * 128 + v] > 0.5f) t = v;
    tok[l] = t;
}

// ---------------- STFT conv1 (3x3x1->256) + relu + 2x2 maxpool ----------------
// in [64,513], out [31,255,256]
__global__ void stft_conv1_kernel(const float* __restrict__ in, const float* __restrict__ w,
                                  const float* __restrict__ b, float* __restrict__ out) {
    int c = threadIdx.x;
    int blk = blockIdx.x;
    int pw = blk % 255, ph = blk / 255;
    int h0 = 2 * ph, w0 = 2 * pw;
    float pin[4][4];
#pragma unroll
    for (int r = 0; r < 4; ++r)
#pragma unroll
        for (int s = 0; s < 4; ++s) pin[r][s] = in[(h0 + r) * 513 + (w0 + s)];
    float acc[2][2] = {};
#pragma unroll
    for (int dh = 0; dh < 3; ++dh)
#pragma unroll
        for (int dw = 0; dw < 3; ++dw) {
            float wv = w[(dh * 3 + dw) * 256 + c];
            acc[0][0] += pin[dh][dw] * wv;
            acc[0][1] += pin[dh][dw + 1] * wv;
            acc[1][0] += pin[dh + 1][dw] * wv;
            acc[1][1] += pin[dh + 1][dw + 1] * wv;
        }
    float m = fmaxf(fmaxf(acc[0][0], acc[0][1]), fmaxf(acc[1][0], acc[1][1]));
    out[(ph * 255 + pw) * 256 + c] = fmaxf(m + b[c], 0.f);
}

// ---------------- STFT conv2 (3x3x256->256) + relu + 2x2 maxpool ----------------
// in [31,255,256], out [14,126,256]; block = (ph, group of 3 pw), 256 threads = out channel
__global__ void stft_conv2_kernel(const float* __restrict__ P1, const float* __restrict__ w,
                                  const float* __restrict__ b, float* __restrict__ out) {
    __shared__ float patch[4 * 8 * 256];  // [r][cc][ci]
    int c = threadIdx.x;
    int blk = blockIdx.x;
    int pwg = blk % 42, ph = blk / 42;
    int pw0 = pwg * 3;
    int r0 = 2 * ph, c0 = 2 * pw0;
    for (int i = c; i < 4 * 8 * 256; i += 256) {
        int ci = i & 255;
        int t = i >> 8;
        int cc = t & 7, r = t >> 3;
        patch[i] = P1[((r0 + r) * 255 + (c0 + cc)) * 256 + ci];
    }
    __syncthreads();
    float acc[3][2][2] = {};
    for (int dh = 0; dh < 3; ++dh) {
        for (int ci = 0; ci < 256; ++ci) {
            float p0[8], p1[8];
#pragma unroll
            for (int x = 0; x < 8; ++x) {
                p0[x] = patch[(dh * 8 + x) * 256 + ci];
                p1[x] = patch[((dh + 1) * 8 + x) * 256 + ci];
            }
#pragma unroll
            for (int dw = 0; dw < 3; ++dw) {
                float wv = w[((dh * 3 + dw) * 256 + ci) * 256 + c];
#pragma unroll
                for (int o = 0; o < 3; ++o)
#pragma unroll
                    for (int s = 0; s < 2; ++s) {
                        acc[o][0][s] += p0[2 * o + s + dw] * wv;
                        acc[o][1][s] += p1[2 * o + s + dw] * wv;
                    }
            }
        }
    }
    float bv = b[c];
#pragma unroll
    for (int o = 0; o < 3; ++o) {
        float m = fmaxf(fmaxf(acc[o][0][0], acc[o][0][1]), fmaxf(acc[o][1][0], acc[o][1][1]));
        out[(ph * 126 + (pw0 + o)) * 256 + c] = fmaxf(m + bv, 0.f);
    }
}

// ---------------- STFT input projection: X[14,32256] @ Wi[32256,1024], split-K ----------------
__global__ void xprojS_partial_kernel(const float* __restrict__ X, const float* __restrict__ Wi,
                                      float* __restrict__ part) {
    __shared__ float xbuf[14 * 504];
    int tid = threadIdx.x;
    int kc = blockIdx.x & 63;
    int cb = blockIdx.x >> 6;
    int col = cb * 256 + tid;
    int k0 = kc * 504;
    for (int i = tid; i < 14 * 504; i += 256) {
        int t = i / 504;
        int kk = i - t * 504;
        xbuf[i] = X[t * 32256 + k0 + kk];
    }
    __syncthreads();
    float acc[14] = {};
    for (int kk = 0; kk < 504; ++kk) {
        float wv = Wi[(size_t)(k0 + kk) * 1024 + col];
#pragma unroll
        for (int t = 0; t < 14; ++t) acc[t] += xbuf[t * 504 + kk] * wv;
    }
#pragma unroll
    for (int t = 0; t < 14; ++t) part[(kc * 14 + t) * 1024 + col] = acc[t];
}

__global__ void xprojS_reduce_kernel(const float* __restrict__ part, const float* __restrict__ bias,
                                     float* __restrict__ xp) {
    int idx = blockIdx.x * 256 + threadIdx.x;  // < 14*1024
    int t = idx >> 10, col = idx & 1023;
    float s = bias[col];
    for (int kc = 0; kc < 64; ++kc) s += part[(kc * 14 + t) * 1024 + col];
    xp[idx] = s;
}

// ---------------- wave conv1 (k=3, 1024->256) + relu + pool2 ----------------
// in [256,1024], out [127,256]
__global__ void wave_conv1_kernel(const float* __restrict__ in, const float* __restrict__ w,
                                  const float* __restrict__ b, float* __restrict__ out) {
    __shared__ float patch[4 * 1024];
    int c = threadIdx.x, t = blockIdx.x;
    for (int i = c; i < 4 * 1024; i += 256) patch[i] = in[(2 * t) * 1024 + i];
    __syncthreads();
    float acc0 = 0.f, acc1 = 0.f;
    for (int dt = 0; dt < 3; ++dt)
        for (int ci = 0; ci < 1024; ++ci) {
            float wv = w[(dt * 1024 + ci) * 256 + c];
            acc0 += patch[dt * 1024 + ci] * wv;
            acc1 += patch[(dt + 1) * 1024 + ci] * wv;
        }
    out[t * 256 + c] = fmaxf(fmaxf(acc0, acc1) + b[c], 0.f);
}

// ---------------- wave conv2 (k=3, 256->256) + relu + pool2 ----------------
// in [127,256], out [62,256]
__global__ void wave_conv2_kernel(const float* __restrict__ in, const float* __restrict__ w,
                                  const float* __restrict__ b, float* __restrict__ out) {
    __shared__ float patch[4 * 256];
    int c = threadIdx.x, t = blockIdx.x;
    for (int i = c; i < 4 * 256; i += 256) patch[i] = in[(2 * t) * 256 + i];
    __syncthreads();
    float acc0 = 0.f, acc1 = 0.f;
    for (int dt = 0; dt < 3; ++dt)
        for (int ci = 0; ci < 256; ++ci) {
            float wv = w[(dt * 256 + ci) * 256 + c];
            acc0 += patch[dt * 256 + ci] * wv;
            acc1 += patch[(dt + 1) * 256 + ci] * wv;
        }
    out[t * 256 + c] = fmaxf(fmaxf(acc0, acc1) + b[c], 0.f);
}

// ---------------- wave input projection X[62,256] @ Wi[256,1024] + b ----------------
__global__ void xprojW_kernel(const float* __restrict__ X, const float* __restrict__ Wi,
                              const float* __restrict__ bias, float* __restrict__ xp) {
    int idx = blockIdx.x * 256 + threadIdx.x;  // 62*1024
    int t = idx >> 10, col = idx & 1023;
    float s = bias[col];
    for (int k = 0; k < 256; ++k) s += X[t * 256 + k] * Wi[k * 1024 + col];
    xp[idx] = s;
}

// ---------------- encoder LSTM (xproj precomputed, bias folded in), h0=c0=0 ----------------
// __launch_bounds__(1024, 4): 16 waves/block = 4 waves/EU -> VGPR budget 512/thread,
// keeps the 256-reg Wh column resident (R0 regression: default bound -> 64 VGPR -> full spill)
__global__ __launch_bounds__(1024, 4) void lstm_enc_kernel(const float* __restrict__ xp,
                                                        const float* __restrict__ Wh, int T,
                                                        float* __restrict__ h_out,
                                                        float* __restrict__ c_out) {
    __shared__ __align__(16) float hbuf[256];
    __shared__ float zbuf[1024];
    int j = threadIdx.x;
    v2f wreg[128];
#pragma unroll
    for (int kk = 0; kk < 128; ++kk)
        wreg[kk] = mk2(Wh[(2 * kk) * 1024 + j], Wh[(2 * kk + 1) * 1024 + j]);
    float c = 0.f;
    if (j < 256) hbuf[j] = 0.f;
    __syncthreads();
    for (int t = 0; t < T; ++t) {
        float z = xp[t * 1024 + j] + dot256(wreg, (const float4*)hbuf);
        zbuf[j] = z;
        __syncthreads();
        if (j < 256) {
            float zi = zbuf[j], zf = zbuf[j + 256], zg = zbuf[j + 512], zo = zbuf[j + 768];
            c = sigmoidf_(zf) * c + sigmoidf_(zi) * tanhf_(zg);
            hbuf[j] = sigmoidf_(zo) * tanhf_(c);
        }
        __syncthreads();
    }
    if (j < 256) {
        h_out[j] = hbuf[j];
        c_out[j] = c;
    }
}

// ---------------- state reducers: [sh|wh]@rh_w+rh_b, [sc|wc]@rc_w+rc_b ----------------
__global__ void reduce_state_kernel(const float* __restrict__ sh, const float* __restrict__ sc,
                                    const float* __restrict__ wh, const float* __restrict__ wc,
                                    const float* __restrict__ rhw, const float* __restrict__ rhb,
                                    const float* __restrict__ rcw, const float* __restrict__ rcb,
                                    float* __restrict__ h0, float* __restrict__ c0) {
    int m = threadIdx.x;  // 256
    float ah = rhb[m], ac = rcb[m];
    for (int k = 0; k < 256; ++k) {
        ah += sh[k] * rhw[k * 256 + m];
        ac += sc[k] * rcw[k * 256 + m];
    }
    for (int k = 0; k < 256; ++k) {
        ah += wh[k] * rhw[(256 + k) * 256 + m];
        ac += wc[k] * rcw[(256 + k) * 256 + m];
    }
    h0[m] = ah;
    c0[m] = ac;
}

// ---------------- a0/a1 = emb[s] @ d_Wi + d_b ----------------
__global__ void a01_kernel(const float* __restrict__ emb, const float* __restrict__ Wi,
                           const float* __restrict__ bias, float* __restrict__ a01) {
    int idx = blockIdx.x * 256 + threadIdx.x;  // 2048
    int s = idx >> 10, j = idx & 1023;
    float acc = bias[j];
    for (int k = 0; k < 256; ++k) acc += emb[s * 256 + k] * Wi[k * 1024 + j];
    a01[idx] = acc;
}

// ---------------- decoder chain: 38272 sequential LSTM steps, h history -> bf16 ----------------
__global__ __launch_bounds__(1024, 4) void lstm_dec_kernel(
    const float* __restrict__ Wh, const float* __restrict__ a0, const float* __restrict__ a1,
    const int* __restrict__ tok, const float* __restrict__ h0, const float* __restrict__ c0,
    __hip_bfloat16* __restrict__ h_hist) {
    __shared__ __align__(16) float hbuf[256];
    __shared__ float zbuf[1024];
    int j = threadIdx.x;
    v2f wreg[128];
#pragma unroll
    for (int kk = 0; kk < 128; ++kk)
        wreg[kk] = mk2(Wh[(2 * kk) * 1024 + j], Wh[(2 * kk + 1) * 1024 + j]);
    float a0r = a0[j], a1r = a1[j];
    float c = 0.f;
    if (j < 256) {
        hbuf[j] = h0[j];
        c = c0[j];
    }
    __syncthreads();
    int step = 0;
#pragma unroll 1
    for (int l = 0; l < 299; ++l) {
        int tk = tok[l];
#pragma unroll 1
        for (int v = 0; v < 128; ++v) {
            float a = (v == tk) ? a1r : a0r;
            float z = a + dot256(wreg, (const float4*)hbuf);
            zbuf[j] = z;
            __syncthreads();
            if (j < 256) {
                float zi = zbuf[j], zf = zbuf[j + 256], zg = zbuf[j + 512], zo = zbuf[j + 768];
                c = sigmoidf_(zf) * c + sigmoidf_(zi) * tanhf_(zg);
                float h = sigmoidf_(zo) * tanhf_(c);
                hbuf[j] = h;
                h_hist[(size_t)step * 256 + j] = __float2bfloat16(h);
            }
            __syncthreads();
            ++step;
        }
    }
}

// ---------------- projection + softmax epilogue: 4 rows/block, 256 threads ----------------
__global__ __launch_bounds__(256) void proj_softmax_kernel(const __hip_bfloat16* __restrict__ hh,
                                                           const float* __restrict__ Wo,
                                                           const float* __restrict__ bo,
                                                           float* __restrict__ out) {
    __shared__ float hrows[4][256];
    __shared__ float llds[4][128];
    int tid = threadIdx.x;
    int rbase = blockIdx.x * 4;
    for (int i = tid; i < 1024; i += 256)
        hrows[i >> 8][i & 255] = __bfloat162float(hh[(size_t)rbase * 256 + i]);
    __syncthreads();
    int w = tid & 127, half = tid >> 7;
    int k0 = half * 128;
    float acc[4] = {};
    for (int k = 0; k < 128; ++k) {
        float wv = Wo[(k0 + k) * 128 + w];
#pragma unroll
        for (int r = 0; r < 4; ++r) acc[r] += hrows[r][k0 + k] * wv;
    }
    if (half == 0) {
#pragma unroll
        for (int r = 0; r < 4; ++r) llds[r][w] = acc[r] + bo[w];
    }
    __syncthreads();
    if (half == 1) {
#pragma unroll
        for (int r = 0; r < 4; ++r) llds[r][w] += acc[r];
    }
    __syncthreads();
    int rr = tid >> 6, lane = tid & 63;  // wave rr handles row rr
    float x0 = llds[rr][lane], x1 = llds[rr][lane + 64];
    float mx = fmaxf(x0, x1);
    for (int off = 32; off > 0; off >>= 1) mx = fmaxf(mx, __shfl_xor(mx, off));
    float e0 = __expf(x0 - mx), e1 = __expf(x1 - mx);
    float sm = e0 + e1;
    for (int off = 32; off > 0; off >>= 1) sm += __shfl_xor(sm, off);
    float inv = 1.f / sm;
    int row = rbase + rr;
    int l = row >> 7, v = row & 127;
    float* op = out + ((size_t)v * 300 + l) * 128;
    op[lane] = e0 * inv;
    op[lane + 64] = e1 * inv;
}

// ---------------- zero last time slot l=299 ----------------
__global__ void zero_tail_kernel(float* __restrict__ out) {
    int idx = blockIdx.x * 256 + threadIdx.x;  // 128*128
    int v = idx >> 7, w = idx & 127;
    out[((size_t)v * 300 + 299) * 128 + w] = 0.f;
}

extern "C" void kernel_launch(void* const* d_in, const int* in_sizes, int n_in, void* d_out,
                              int out_size, void* d_ws, size_t ws_size, hipStream_t stream) {
    const float* stft = (const float*)d_in[0];
    const float* wave = (const float*)d_in[1];
    const float* din = (const float*)d_in[2];
    const float* s_cw1 = (const float*)d_in[3];
    const float* s_cb1 = (const float*)d_in[4];
    const float* s_cw2 = (const float*)d_in[5];
    const float* s_cb2 = (const float*)d_in[6];
    const float* s_Wi = (const float*)d_in[7];
    const float* s_Wh = (const float*)d_in[8];
    const float* s_b = (const float*)d_in[9];
    const float* w_cw1 = (const float*)d_in[10];
    const float* w_cb1 = (const float*)d_in[11];
    const float* w_cw2 = (const float*)d_in[12];
    const float* w_cb2 = (const float*)d_in[13];
    const float* w_Wi = (const float*)d_in[14];
    const float* w_Wh = (const float*)d_in[15];
    const float* w_b = (const float*)d_in[16];
    const float* rh_w = (const float*)d_in[17];
    const float* rh_b = (const float*)d_in[18];
    const float* rc_w = (const float*)d_in[19];
    const float* rc_b = (const float*)d_in[20];
    const float* emb = (const float*)d_in[21];
    const float* d_Wi = (const float*)d_in[22];
    const float* d_Wh = (const float*)d_in[23];
    const float* d_b = (const float*)d_in[24];
    const float* out_w = (const float*)d_in[25];
    const float* out_b = (const float*)d_in[26];
    float* out = (float*)d_out;
    float* ws = (float*)d_ws;

    // workspace layout (float offsets)
    const size_t off_P1s = 0;                         // 31*255*256 = 2023680
    const size_t off_P2s = off_P1s + 2023680;         // 14*126*256 = 451584
    const size_t off_partS = off_P2s + 451584;        // 64*14*1024 = 917504
    const size_t off_P1w = off_partS + 917504;        // 127*256 = 32512
    const size_t off_P2w = off_P1w + 32512;           // 62*256 = 15872
    const size_t off_xprojS = off_P2w + 15872;        // 14*1024
    const size_t off_xprojW = off_xprojS + 14336;     // 62*1024
    const size_t off_sh = off_xprojW + 63488;         // 4*256 states
    const size_t off_sc = off_sh + 256;
    const size_t off_wh = off_sc + 256;
    const size_t off_wc = off_wh + 256;
    const size_t off_h0 = off_wc + 256;
    const size_t off_c0 = off_h0 + 256;
    const size_t off_a01 = off_c0 + 256;              // 2048
    const size_t off_tok = off_a01 + 2048;            // 299 ints (512 slots)
    const size_t off_hh = off_tok + 512;              // bf16 region: 38272*256 bf16
    __hip_bfloat16* h_hist = (__hip_bfloat16*)(ws + off_hh);
    int* tok = (int*)(ws + off_tok);

    tok_kernel<<<5, 64, 0, stream>>>(din, tok);

    // STFT branch
    stft_conv1_kernel<<<31 * 255, 256, 0, stream>>>(stft, s_cw1, s_cb1, ws + off_P1s);
    stft_conv2_kernel<<<14 * 42, 256, 0, stream>>>(ws + off_P1s, s_cw2, s_cb2, ws + off_P2s);
    xprojS_partial_kernel<<<256, 256, 0, stream>>>(ws + off_P2s, s_Wi, ws + off_partS);
    xprojS_reduce_kernel<<<56, 256, 0, stream>>>(ws + off_partS, s_b, ws + off_xprojS);
    lstm_enc_kernel<<<1, 1024, 0, stream>>>(ws + off_xprojS, s_Wh, 14, ws + off_sh, ws + off_sc);

    // waveform branch
    wave_conv1_kernel<<<127, 256, 0, stream>>>(wave, w_cw1, w_cb1, ws + off_P1w);
    wave_conv2_kernel<<<62, 256, 0, stream>>>(ws + off_P1w, w_cw2, w_cb2, ws + off_P2w);
    xprojW_kernel<<<248, 256, 0, stream>>>(ws + off_P2w, w_Wi, w_b, ws + off_xprojW);
    lstm_enc_kernel<<<1, 1024, 0, stream>>>(ws + off_xprojW, w_Wh, 62, ws + off_wh, ws + off_wc);

    // reducers + decoder precompute
    reduce_state_kernel<<<1, 256, 0, stream>>>(ws + off_sh, ws + off_sc, ws + off_wh, ws + off_wc,
                                               rh_w, rh_b, rc_w, rc_b, ws + off_h0, ws + off_c0);
    a01_kernel<<<8, 256, 0, stream>>>(emb, d_Wi, d_b, ws + off_a01);

    // sequential decoder chain (critical path)
    lstm_dec_kernel<<<1, 1024, 0, stream>>>(d_Wh, ws + off_a01, ws + off_a01 + 1024, tok,
                                            ws + off_h0, ws + off_c0, h_hist);

    // parallel epilogue
    proj_softmax_kernel<<<NSTEP / 4, 256, 0, stream>>>(h_hist, out_w, out_b, out);
    zero_tail_kernel<<<64, 256, 0, stream>>>(out);
}

// Round 3
// 96706.152 us; speedup vs baseline: 7.1868x; 7.1868x over previous
//
#include <hip/hip_runtime.h>
#include <hip/hip_bf16.h>
#include <stdint.h>

// ---------------- model dims ----------------
#define V_   128
#define L_   300
#define EU_  256
#define GU_  1024    // 4*EU
#define NSTEP (299*128)   // 38272 decoder steps

// f16x2 packed weight layout constants (per 256x1024 Wh matrix, total 131072 dwords):
//   wr4  [28][1024][4] dwords : k-pairs kp=4q+p (k=2kp,2kp+1), register-resident portion (k<224)
//   wr1  [1024] dwords        : kp=112 (k=224,225)
//   wlds [15][1024] dwords    : kp=113..127 (k=226..255), LDS-streamed portion
#define N_G4     28
#define W1_OFF   114688
#define WLDS_OFF 115712
#define N_KLDS   15

typedef _Float16 h2 __attribute__((ext_vector_type(2)));

__device__ __forceinline__ float sigmoidf_(float x) { return 1.f / (1.f + __expf(-x)); }
__device__ __forceinline__ float tanhf_(float x) { return 2.f / (1.f + __expf(-2.f * x)) - 1.f; }

#if __has_builtin(__builtin_amdgcn_fdot2)
__device__ __forceinline__ float fdot2_(h2 a, h2 b, float c) { return __builtin_amdgcn_fdot2(a, b, c, false); }
#else
__device__ __forceinline__ float fdot2_(h2 a, h2 b, float c) {
    return c + (float)a.x * (float)b.x + (float)a.y * (float)b.y;
}
#endif

__device__ __forceinline__ h2 bch2(uint32_t u) {
    union { uint32_t u; h2 h; } x; x.u = u; return x.h;
}

// ---------------- weight repack: fp32 Wh[256][1024] -> packed f16x2 layout ----------------
__global__ void prep_wh_kernel(const float* __restrict__ Wh, uint32_t* __restrict__ wbuf) {
    int idx = blockIdx.x * 256 + threadIdx.x;  // 131072 total (512 blocks)
    int kp = idx >> 10, col = idx & 1023;
    union { _Float16 f[2]; uint32_t u; } p;
    p.f[0] = (_Float16)Wh[(2 * kp) * 1024 + col];
    p.f[1] = (_Float16)Wh[(2 * kp + 1) * 1024 + col];
    if (kp < 112) wbuf[((kp >> 2) * 1024 + col) * 4 + (kp & 3)] = p.u;
    else if (kp == 112) wbuf[W1_OFF + col] = p.u;
    else wbuf[WLDS_OFF + (kp - 113) * 1024 + col] = p.u;
}

// thread j owns gate columns {j, j+256, j+512, j+768}; weights k<226 in VGPRs, rest in LDS
__device__ __forceinline__ void load_weights(const uint32_t* __restrict__ wbuf, int j,
                                             uint4 (&wr)[4][N_G4], uint32_t (&w1)[4]) {
    const uint4* w4 = (const uint4*)wbuf;
#pragma unroll
    for (int g = 0; g < 4; ++g) {
        int col = j + 256 * g;
#pragma unroll
        for (int q = 0; q < N_G4; ++q) wr[g][q] = w4[q * 1024 + col];
        w1[g] = wbuf[W1_OFF + col];
    }
}

__device__ __forceinline__ void dots4(const uint4 (&wr)[4][N_G4], const uint32_t (&w1)[4],
                                      const uint32_t* hp, const uint32_t* wlds_s, int j,
                                      float (&acc)[4]) {
#pragma unroll
    for (int g = 0; g < 4; ++g) acc[g] = 0.f;
#pragma unroll
    for (int q = 0; q < N_G4; ++q) {
        uint4 hv = *(const uint4*)(hp + 4 * q);  // LDS b128 broadcast (all lanes same addr)
#pragma unroll
        for (int g = 0; g < 4; ++g) {
            uint4 w = wr[g][q];
            acc[g] = fdot2_(bch2(w.x), bch2(hv.x), acc[g]);
            acc[g] = fdot2_(bch2(w.y), bch2(hv.y), acc[g]);
            acc[g] = fdot2_(bch2(w.z), bch2(hv.z), acc[g]);
            acc[g] = fdot2_(bch2(w.w), bch2(hv.w), acc[g]);
        }
    }
    {
        uint32_t hv = hp[112];
#pragma unroll
        for (int g = 0; g < 4; ++g) acc[g] = fdot2_(bch2(w1[g]), bch2(hv), acc[g]);
    }
#pragma unroll
    for (int kk = 0; kk < N_KLDS; ++kk) {
        uint32_t hv = hp[113 + kk];
#pragma unroll
        for (int g = 0; g < 4; ++g)
            acc[g] = fdot2_(bch2(wlds_s[kk * 1024 + j + 256 * g]), bch2(hv), acc[g]);
    }
}

// ---------------- encoder LSTM: 256 thr, 1 wave/EU -> 512-VGPR budget ----------------
__global__ __launch_bounds__(256, 1) void lstm_enc2_kernel(const uint32_t* __restrict__ wbuf,
                                                           const float* __restrict__ xp, int T,
                                                           float* __restrict__ h_out,
                                                           float* __restrict__ c_out) {
    __shared__ uint32_t wlds_s[N_KLDS * 1024];   // 60 KiB
    __shared__ uint32_t h_pk[2][128];            // h as f16x2, parity double-buffered
    int j = threadIdx.x;
    uint4 wr[4][N_G4]; uint32_t w1[4];
    load_weights(wbuf, j, wr, w1);
    for (int i = j; i < N_KLDS * 1024; i += 256) wlds_s[i] = wbuf[WLDS_OFF + i];
    if (j < 128) h_pk[0][j] = 0;
    float c = 0.f, h = 0.f;
    __syncthreads();
    int cur = 0;
    for (int t = 0; t < T; ++t) {
        float acc[4];
        dots4(wr, w1, &h_pk[cur][0], wlds_s, j, acc);
        float zi = acc[0] + xp[t * 1024 + j];
        float zf = acc[1] + xp[t * 1024 + j + 256];
        float zg = acc[2] + xp[t * 1024 + j + 512];
        float zo = acc[3] + xp[t * 1024 + j + 768];
        c = sigmoidf_(zf) * c + sigmoidf_(zi) * tanhf_(zg);
        h = sigmoidf_(zo) * tanhf_(c);
        ((_Float16*)&h_pk[cur ^ 1][0])[j] = (_Float16)h;
        __syncthreads();
        cur ^= 1;
    }
    h_out[j] = h;
    c_out[j] = c;
}

// ---------------- decoder chain with fixed-point fast-forward ----------------
__global__ __launch_bounds__(256, 1) void lstm_dec2_kernel(const uint32_t* __restrict__ wbuf,
                                                           const float* __restrict__ a01,
                                                           const int* __restrict__ tok,
                                                           const float* __restrict__ h0,
                                                           const float* __restrict__ c0,
                                                           __hip_bfloat16* __restrict__ hist) {
    __shared__ uint32_t wlds_s[N_KLDS * 1024];
    __shared__ uint32_t h_pk[2][128];
    __shared__ int flagv[2][4];
    int j = threadIdx.x;
    uint4 wr[4][N_G4]; uint32_t w1[4];
    load_weights(wbuf, j, wr, w1);
    for (int i = j; i < N_KLDS * 1024; i += 256) wlds_s[i] = wbuf[WLDS_OFF + i];
    float a0g[4], a1g[4];
#pragma unroll
    for (int g = 0; g < 4; ++g) {
        a0g[g] = a01[j + 256 * g];
        a1g[g] = a01[1024 + j + 256 * g];
    }
    float h = h0[j], c = c0[j];
    ((_Float16*)&h_pk[0][0])[j] = (_Float16)h;
    __syncthreads();
    int cur = 0;
    bool prev_a0 = false, stat = false;
    int step = 0;
#pragma unroll 1
    for (int l = 0; l < 299; ++l) {
        int tk = tok[l];
        int v = 0;
        while (v < 128) {
            if (stat && v != tk) {
                // state is stationary under a0 input: fast-forward to next perturbation
                int nxt = (v < tk) ? tk : 128;
                __hip_bfloat16 hb = __float2bfloat16(h);
                for (int s = v; s < nxt; ++s)
                    hist[(size_t)(step + (s - v)) * 256 + j] = hb;
                step += nxt - v;
                v = nxt;
                continue;
            }
            bool isa1 = (v == tk);
            float acc[4];
            dots4(wr, w1, &h_pk[cur][0], wlds_s, j, acc);
            float zi = acc[0] + (isa1 ? a1g[0] : a0g[0]);
            float zf = acc[1] + (isa1 ? a1g[1] : a0g[1]);
            float zg = acc[2] + (isa1 ? a1g[2] : a0g[2]);
            float zo = acc[3] + (isa1 ? a1g[3] : a0g[3]);
            float cn = sigmoidf_(zf) * c + sigmoidf_(zi) * tanhf_(zg);
            float hn = sigmoidf_(zo) * tanhf_(cn);
            bool ok = (fabsf(hn - h) <= 1e-6f) && (fabsf(cn - c) <= 1e-6f) && !isa1 && prev_a0;
            unsigned long long bal = __ballot(ok ? 1 : 0);
            if ((j & 63) == 0) flagv[cur][j >> 6] = (bal == ~0ull) ? 1 : 0;
            h = hn;
            c = cn;
            hist[(size_t)step * 256 + j] = __float2bfloat16(h);
            ((_Float16*)&h_pk[cur ^ 1][0])[j] = (_Float16)h;
            __syncthreads();
            stat = flagv[cur][0] && flagv[cur][1] && flagv[cur][2] && flagv[cur][3];
            cur ^= 1;
            prev_a0 = !isa1;
            ++step;
            ++v;
        }
    }
}

// ---------------- tok extraction ----------------
__global__ void tok_kernel(const float* __restrict__ din, int* __restrict__ tok) {
    int l = blockIdx.x * 64 + threadIdx.x;
    if (l >= 299) return;
    int t = 0;
    for (int v = 0; v < 128; ++v)
        if (din[l * 128 + v] > 0.5f) t = v;
    tok[l] = t;
}

// ---------------- STFT conv1 (3x3x1->256) + relu + 2x2 maxpool ----------------
__global__ void stft_conv1_kernel(const float* __restrict__ in, const float* __restrict__ w,
                                  const float* __restrict__ b, float* __restrict__ out) {
    int c = threadIdx.x;
    int blk = blockIdx.x;
    int pw = blk % 255, ph = blk / 255;
    int h0 = 2 * ph, w0 = 2 * pw;
    float pin[4][4];
#pragma unroll
    for (int r = 0; r < 4; ++r)
#pragma unroll
        for (int s = 0; s < 4; ++s) pin[r][s] = in[(h0 + r) * 513 + (w0 + s)];
    float acc[2][2] = {};
#pragma unroll
    for (int dh = 0; dh < 3; ++dh)
#pragma unroll
        for (int dw = 0; dw < 3; ++dw) {
            float wv = w[(dh * 3 + dw) * 256 + c];
            acc[0][0] += pin[dh][dw] * wv;
            acc[0][1] += pin[dh][dw + 1] * wv;
            acc[1][0] += pin[dh + 1][dw] * wv;
            acc[1][1] += pin[dh + 1][dw + 1] * wv;
        }
    float m = fmaxf(fmaxf(acc[0][0], acc[0][1]), fmaxf(acc[1][0], acc[1][1]));
    out[(ph * 255 + pw) * 256 + c] = fmaxf(m + b[c], 0.f);
}

// ---------------- STFT conv2 (3x3x256->256) + relu + 2x2 maxpool ----------------
__global__ void stft_conv2_kernel(const float* __restrict__ P1, const float* __restrict__ w,
                                  const float* __restrict__ b, float* __restrict__ out) {
    __shared__ float patch[4 * 8 * 256];
    int c = threadIdx.x;
    int blk = blockIdx.x;
    int pwg = blk % 42, ph = blk / 42;
    int pw0 = pwg * 3;
    int r0 = 2 * ph, c0 = 2 * pw0;
    for (int i = c; i < 4 * 8 * 256; i += 256) {
        int ci = i & 255;
        int t = i >> 8;
        int cc = t & 7, r = t >> 3;
        patch[i] = P1[((r0 + r) * 255 + (c0 + cc)) * 256 + ci];
    }
    __syncthreads();
    float acc[3][2][2] = {};
    for (int dh = 0; dh < 3; ++dh) {
        for (int ci = 0; ci < 256; ++ci) {
            float p0[8], p1[8];
#pragma unroll
            for (int x = 0; x < 8; ++x) {
                p0[x] = patch[(dh * 8 + x) * 256 + ci];
                p1[x] = patch[((dh + 1) * 8 + x) * 256 + ci];
            }
#pragma unroll
            for (int dw = 0; dw < 3; ++dw) {
                float wv = w[((dh * 3 + dw) * 256 + ci) * 256 + c];
#pragma unroll
                for (int o = 0; o < 3; ++o)
#pragma unroll
                    for (int s = 0; s < 2; ++s) {
                        acc[o][0][s] += p0[2 * o + s + dw] * wv;
                        acc[o][1][s] += p1[2 * o + s + dw] * wv;
                    }
            }
        }
    }
    float bv = b[c];
#pragma unroll
    for (int o = 0; o < 3; ++o) {
        float m = fmaxf(fmaxf(acc[o][0][0], acc[o][0][1]), fmaxf(acc[o][1][0], acc[o][1][1]));
        out[(ph * 126 + (pw0 + o)) * 256 + c] = fmaxf(m + bv, 0.f);
    }
}

// ---------------- STFT input projection: X[14,32256] @ Wi[32256,1024], split-K ----------------
__global__ void xprojS_partial_kernel(const float* __restrict__ X, const float* __restrict__ Wi,
                                      float* __restrict__ part) {
    __shared__ float xbuf[14 * 504];
    int tid = threadIdx.x;
    int kc = blockIdx.x & 63;
    int cb = blockIdx.x >> 6;
    int col = cb * 256 + tid;
    int k0 = kc * 504;
    for (int i = tid; i < 14 * 504; i += 256) {
        int t = i / 504;
        int kk = i - t * 504;
        xbuf[i] = X[t * 32256 + k0 + kk];
    }
    __syncthreads();
    float acc[14] = {};
    for (int kk = 0; kk < 504; ++kk) {
        float wv = Wi[(size_t)(k0 + kk) * 1024 + col];
#pragma unroll
        for (int t = 0; t < 14; ++t) acc[t] += xbuf[t * 504 + kk] * wv;
    }
#pragma unroll
    for (int t = 0; t < 14; ++t) part[(kc * 14 + t) * 1024 + col] = acc[t];
}

__global__ void xprojS_reduce_kernel(const float* __restrict__ part, const float* __restrict__ bias,
                                     float* __restrict__ xp) {
    int idx = blockIdx.x * 256 + threadIdx.x;  // < 14*1024
    int t = idx >> 10, col = idx & 1023;
    float s = bias[col];
    for (int kc = 0; kc < 64; ++kc) s += part[(kc * 14 + t) * 1024 + col];
    xp[idx] = s;
}

// ---------------- wave conv1 (k=3, 1024->256) + relu + pool2 ----------------
__global__ void wave_conv1_kernel(const float* __restrict__ in, const float* __restrict__ w,
                                  const float* __restrict__ b, float* __restrict__ out) {
    __shared__ float patch[4 * 1024];
    int c = threadIdx.x, t = blockIdx.x;
    for (int i = c; i < 4 * 1024; i += 256) patch[i] = in[(2 * t) * 1024 + i];
    __syncthreads();
    float acc0 = 0.f, acc1 = 0.f;
    for (int dt = 0; dt < 3; ++dt)
        for (int ci = 0; ci < 1024; ++ci) {
            float wv = w[(dt * 1024 + ci) * 256 + c];
            acc0 += patch[dt * 1024 + ci] * wv;
            acc1 += patch[(dt + 1) * 1024 + ci] * wv;
        }
    out[t * 256 + c] = fmaxf(fmaxf(acc0, acc1) + b[c], 0.f);
}

// ---------------- wave conv2 (k=3, 256->256) + relu + pool2 ----------------
__global__ void wave_conv2_kernel(const float* __restrict__ in, const float* __restrict__ w,
                                  const float* __restrict__ b, float* __restrict__ out) {
    __shared__ float patch[4 * 256];
    int c = threadIdx.x, t = blockIdx.x;
    for (int i = c; i < 4 * 256; i += 256) patch[i] = in[(2 * t) * 256 + i];
    __syncthreads();
    float acc0 = 0.f, acc1 = 0.f;
    for (int dt = 0; dt < 3; ++dt)
        for (int ci = 0; ci < 256; ++ci) {
            float wv = w[(dt * 256 + ci) * 256 + c];
            acc0 += patch[dt * 256 + ci] * wv;
            acc1 += patch[(dt + 1) * 256 + ci] * wv;
        }
    out[t * 256 + c] = fmaxf(fmaxf(acc0, acc1) + b[c], 0.f);
}

// ---------------- wave input projection X[62,256] @ Wi[256,1024] + b ----------------
__global__ void xprojW_kernel(const float* __restrict__ X, const float* __restrict__ Wi,
                              const float* __restrict__ bias, float* __restrict__ xp) {
    int idx = blockIdx.x * 256 + threadIdx.x;  // 62*1024
    int t = idx >> 10, col = idx & 1023;
    float s = bias[col];
    for (int k = 0; k < 256; ++k) s += X[t * 256 + k] * Wi[k * 1024 + col];
    xp[idx] = s;
}

// ---------------- state reducers ----------------
__global__ void reduce_state_kernel(const float* __restrict__ sh, const float* __restrict__ sc,
                                    const float* __restrict__ wh, const float* __restrict__ wc,
                                    const float* __restrict__ rhw, const float* __restrict__ rhb,
                                    const float* __restrict__ rcw, const float* __restrict__ rcb,
                                    float* __restrict__ h0, float* __restrict__ c0) {
    int m = threadIdx.x;  // 256
    float ah = rhb[m], ac = rcb[m];
    for (int k = 0; k < 256; ++k) {
        ah += sh[k] * rhw[k * 256 + m];
        ac += sc[k] * rcw[k * 256 + m];
    }
    for (int k = 0; k < 256; ++k) {
        ah += wh[k] * rhw[(256 + k) * 256 + m];
        ac += wc[k] * rcw[(256 + k) * 256 + m];
    }
    h0[m] = ah;
    c0[m] = ac;
}

// ---------------- a0/a1 = emb[s] @ d_Wi + d_b ----------------
__global__ void a01_kernel(const float* __restrict__ emb, const float* __restrict__ Wi,
                           const float* __restrict__ bias, float* __restrict__ a01) {
    int idx = blockIdx.x * 256 + threadIdx.x;  // 2048
    int s = idx >> 10, j = idx & 1023;
    float acc = bias[j];
    for (int k = 0; k < 256; ++k) acc += emb[s * 256 + k] * Wi[k * 1024 + j];
    a01[idx] = acc;
}

// ---------------- projection + softmax epilogue: 4 rows/block, 256 threads ----------------
__global__ __launch_bounds__(256) void proj_softmax_kernel(const __hip_bfloat16* __restrict__ hh,
                                                           const float* __restrict__ Wo,
                                                           const float* __restrict__ bo,
                                                           float* __restrict__ out) {
    __shared__ float hrows[4][256];
    __shared__ float llds[4][128];
    int tid = threadIdx.x;
    int rbase = blockIdx.x * 4;
    for (int i = tid; i < 1024; i += 256)
        hrows[i >> 8][i & 255] = __bfloat162float(hh[(size_t)rbase * 256 + i]);
    __syncthreads();
    int w = tid & 127, half = tid >> 7;
    int k0 = half * 128;
    float acc[4] = {};
    for (int k = 0; k < 128; ++k) {
        float wv = Wo[(k0 + k) * 128 + w];
#pragma unroll
        for (int r = 0; r < 4; ++r) acc[r] += hrows[r][k0 + k] * wv;
    }
    if (half == 0) {
#pragma unroll
        for (int r = 0; r < 4; ++r) llds[r][w] = acc[r] + bo[w];
    }
    __syncthreads();
    if (half == 1) {
#pragma unroll
        for (int r = 0; r < 4; ++r) llds[r][w] += acc[r];
    }
    __syncthreads();
    int rr = tid >> 6, lane = tid & 63;
    float x0 = llds[rr][lane], x1 = llds[rr][lane + 64];
    float mx = fmaxf(x0, x1);
    for (int off = 32; off > 0; off >>= 1) mx = fmaxf(mx, __shfl_xor(mx, off));
    float e0 = __expf(x0 - mx), e1 = __expf(x1 - mx);
    float sm = e0 + e1;
    for (int off = 32; off > 0; off >>= 1) sm += __shfl_xor(sm, off);
    float inv = 1.f / sm;
    int row = rbase + rr;
    int l = row >> 7, v = row & 127;
    float* op = out + ((size_t)v * 300 + l) * 128;
    op[lane] = e0 * inv;
    op[lane + 64] = e1 * inv;
}

// ---------------- zero last time slot l=299 ----------------
__global__ void zero_tail_kernel(float* __restrict__ out) {
    int idx = blockIdx.x * 256 + threadIdx.x;  // 128*128
    int v = idx >> 7, w = idx & 127;
    out[((size_t)v * 300 + 299) * 128 + w] = 0.f;
}

extern "C" void kernel_launch(void* const* d_in, const int* in_sizes, int n_in, void* d_out,
                              int out_size, void* d_ws, size_t ws_size, hipStream_t stream) {
    const float* stft = (const float*)d_in[0];
    const float* wave = (const float*)d_in[1];
    const float* din = (const float*)d_in[2];
    const float* s_cw1 = (const float*)d_in[3];
    const float* s_cb1 = (const float*)d_in[4];
    const float* s_cw2 = (const float*)d_in[5];
    const float* s_cb2 = (const float*)d_in[6];
    const float* s_Wi = (const float*)d_in[7];
    const float* s_Wh = (const float*)d_in[8];
    const float* s_b = (const float*)d_in[9];
    const float* w_cw1 = (const float*)d_in[10];
    const float* w_cb1 = (const float*)d_in[11];
    const float* w_cw2 = (const float*)d_in[12];
    const float* w_cb2 = (const float*)d_in[13];
    const float* w_Wi = (const float*)d_in[14];
    const float* w_Wh = (const float*)d_in[15];
    const float* w_b = (const float*)d_in[16];
    const float* rh_w = (const float*)d_in[17];
    const float* rh_b = (const float*)d_in[18];
    const float* rc_w = (const float*)d_in[19];
    const float* rc_b = (const float*)d_in[20];
    const float* emb = (const float*)d_in[21];
    const float* d_Wi = (const float*)d_in[22];
    const float* d_Wh = (const float*)d_in[23];
    const float* d_b = (const float*)d_in[24];
    const float* out_w = (const float*)d_in[25];
    const float* out_b = (const float*)d_in[26];
    float* out = (float*)d_out;
    float* ws = (float*)d_ws;

    // workspace layout (float offsets)
    const size_t off_P1s = 0;                         // 31*255*256 = 2023680 (reused for packed weights after conv2)
    const size_t off_P2s = off_P1s + 2023680;         // 14*126*256 = 451584
    const size_t off_partS = off_P2s + 451584;        // 64*14*1024 = 917504
    const size_t off_P1w = off_partS + 917504;        // 127*256 = 32512
    const size_t off_P2w = off_P1w + 32512;           // 62*256 = 15872
    const size_t off_xprojS = off_P2w + 15872;        // 14*1024
    const size_t off_xprojW = off_xprojS + 14336;     // 62*1024
    const size_t off_sh = off_xprojW + 63488;         // 4*256 states
    const size_t off_sc = off_sh + 256;
    const size_t off_wh = off_sc + 256;
    const size_t off_wc = off_wh + 256;
    const size_t off_h0 = off_wc + 256;
    const size_t off_c0 = off_h0 + 256;
    const size_t off_a01 = off_c0 + 256;              // 2048
    const size_t off_tok = off_a01 + 2048;            // 299 ints (512 slots)
    const size_t off_hh = off_tok + 512;              // bf16 region: 38272*256 bf16
    __hip_bfloat16* h_hist = (__hip_bfloat16*)(ws + off_hh);
    int* tok = (int*)(ws + off_tok);
    // packed f16 weights overlay the P1s region (free after stft_conv2): 3 x 131072 dwords
    uint32_t* wrS = (uint32_t*)(ws + off_P1s);
    uint32_t* wrW = wrS + 131072;
    uint32_t* wrD = wrW + 131072;

    tok_kernel<<<5, 64, 0, stream>>>(din, tok);

    // STFT conv pipeline (P1s in use until stft_conv2 completes)
    stft_conv1_kernel<<<31 * 255, 256, 0, stream>>>(stft, s_cw1, s_cb1, ws + off_P1s);
    stft_conv2_kernel<<<14 * 42, 256, 0, stream>>>(ws + off_P1s, s_cw2, s_cb2, ws + off_P2s);

    // repack all three Wh matrices into f16x2 layout (P1s region now free)
    prep_wh_kernel<<<512, 256, 0, stream>>>(s_Wh, wrS);
    prep_wh_kernel<<<512, 256, 0, stream>>>(w_Wh, wrW);
    prep_wh_kernel<<<512, 256, 0, stream>>>(d_Wh, wrD);

    xprojS_partial_kernel<<<256, 256, 0, stream>>>(ws + off_P2s, s_Wi, ws + off_partS);
    xprojS_reduce_kernel<<<56, 256, 0, stream>>>(ws + off_partS, s_b, ws + off_xprojS);
    lstm_enc2_kernel<<<1, 256, 0, stream>>>(wrS, ws + off_xprojS, 14, ws + off_sh, ws + off_sc);

    // waveform branch
    wave_conv1_kernel<<<127, 256, 0, stream>>>(wave, w_cw1, w_cb1, ws + off_P1w);
    wave_conv2_kernel<<<62, 256, 0, stream>>>(ws + off_P1w, w_cw2, w_cb2, ws + off_P2w);
    xprojW_kernel<<<248, 256, 0, stream>>>(ws + off_P2w, w_Wi, w_b, ws + off_xprojW);
    lstm_enc2_kernel<<<1, 256, 0, stream>>>(wrW, ws + off_xprojW, 62, ws + off_wh, ws + off_wc);

    // reducers + decoder precompute
    reduce_state_kernel<<<1, 256, 0, stream>>>(ws + off_sh, ws + off_sc, ws + off_wh, ws + off_wc,
                                               rh_w, rh_b, rc_w, rc_b, ws + off_h0, ws + off_c0);
    a01_kernel<<<8, 256, 0, stream>>>(emb, d_Wi, d_b, ws + off_a01);

    // sequential decoder chain (critical path)
    lstm_dec2_kernel<<<1, 256, 0, stream>>>(wrD, ws + off_a01, tok, ws + off_h0, ws + off_c0,
                                            h_hist);

    // parallel epilogue
    proj_softmax_kernel<<<NSTEP / 4, 256, 0, stream>>>(h_hist, out_w, out_b, out);
    zero_tail_kernel<<<64, 256, 0, stream>>>(out);
}

// Round 4
// 93802.954 us; speedup vs baseline: 7.4092x; 1.0309x over previous
//
#include <hip/hip_runtime.h>
#include <hip/hip_bf16.h>
#include <stdint.h>

// ---------------- model dims ----------------
#define V_   128
#define L_   300
#define EU_  256
#define GU_  1024    // 4*EU
#define NSTEP (299*128)   // 38272 decoder steps

// f16x2 packed weight layout constants (per 256x1024 Wh matrix, total 131072 dwords):
//   wr4  [28][1024][4] dwords : k-pairs kp=4q+p (k=2kp,2kp+1), register-resident (k<224)
//   wr1  [1024] dwords        : kp=112 (k=224,225), register-resident
//   wlds [15][256][4] dwords  : kp=113..127 (k=226..255), LDS-resident, [kk][j][g] so a
//                               thread reads its 4 gate weights as ONE ds_read_b128
#define N_G4     28
#define W1_OFF   114688
#define WLDS_OFF 115712
#define N_KLDS   15

typedef _Float16 h2 __attribute__((ext_vector_type(2)));

__device__ __forceinline__ float sigmoidf_(float x) { return 1.f / (1.f + __expf(-x)); }
__device__ __forceinline__ float tanhf_(float x) { return 2.f / (1.f + __expf(-2.f * x)) - 1.f; }

#if __has_builtin(__builtin_amdgcn_fdot2)
__device__ __forceinline__ float fdot2_(h2 a, h2 b, float c) { return __builtin_amdgcn_fdot2(a, b, c, false); }
#else
__device__ __forceinline__ float fdot2_(h2 a, h2 b, float c) {
    return c + (float)a.x * (float)b.x + (float)a.y * (float)b.y;
}
#endif

__device__ __forceinline__ h2 bch2(uint32_t u) {
    union { uint32_t u; h2 h; } x; x.u = u; return x.h;
}

// macro-generated straight-line weight registers: guarantees SROA promotion (R2 regression:
// uint4 wr[4][28] was lowered to scratch -> 448 dwords/thread reloaded every step)
#define Q28(M) M(0) M(1) M(2) M(3) M(4) M(5) M(6) M(7) M(8) M(9) M(10) M(11) M(12) M(13) \
               M(14) M(15) M(16) M(17) M(18) M(19) M(20) M(21) M(22) M(23) M(24) M(25) M(26) M(27)

#define DECLW(q) uint4 wA##q, wB##q, wC##q, wD##q;
#define LOADW(q) wA##q = w4[(q) * 1024 + colA]; wB##q = w4[(q) * 1024 + colB]; \
                 wC##q = w4[(q) * 1024 + colC]; wD##q = w4[(q) * 1024 + colD];
#define DOTQ(q) { uint4 hv = hp4[q]; \
    aA = fdot2_(bch2(wA##q.x), bch2(hv.x), aA); aA = fdot2_(bch2(wA##q.y), bch2(hv.y), aA); \
    aA = fdot2_(bch2(wA##q.z), bch2(hv.z), aA); aA = fdot2_(bch2(wA##q.w), bch2(hv.w), aA); \
    aB = fdot2_(bch2(wB##q.x), bch2(hv.x), aB); aB = fdot2_(bch2(wB##q.y), bch2(hv.y), aB); \
    aB = fdot2_(bch2(wB##q.z), bch2(hv.z), aB); aB = fdot2_(bch2(wB##q.w), bch2(hv.w), aB); \
    aC = fdot2_(bch2(wC##q.x), bch2(hv.x), aC); aC = fdot2_(bch2(wC##q.y), bch2(hv.y), aC); \
    aC = fdot2_(bch2(wC##q.z), bch2(hv.z), aC); aC = fdot2_(bch2(wC##q.w), bch2(hv.w), aC); \
    aD = fdot2_(bch2(wD##q.x), bch2(hv.x), aD); aD = fdot2_(bch2(wD##q.y), bch2(hv.y), aD); \
    aD = fdot2_(bch2(wD##q.z), bch2(hv.z), aD); aD = fdot2_(bch2(wD##q.w), bch2(hv.w), aD); }

// full 256-k dot for this thread's 4 gate columns -> aA..aD
#define DOTS_ALL() \
    float aA = 0.f, aB = 0.f, aC = 0.f, aD = 0.f; \
    { const uint4* hp4 = (const uint4*)hp; \
      Q28(DOTQ) \
      { uint32_t hv = hp[112]; \
        aA = fdot2_(bch2(w1A), bch2(hv), aA); aB = fdot2_(bch2(w1B), bch2(hv), aB); \
        aC = fdot2_(bch2(w1C), bch2(hv), aC); aD = fdot2_(bch2(w1D), bch2(hv), aD); } \
      const uint4* wlds4 = (const uint4*)wlds_s; \
      _Pragma("unroll") \
      for (int kk = 0; kk < N_KLDS; ++kk) { \
          uint32_t hv = hp[113 + kk]; \
          uint4 wv = wlds4[kk * 256 + j]; \
          aA = fdot2_(bch2(wv.x), bch2(hv), aA); aB = fdot2_(bch2(wv.y), bch2(hv), aB); \
          aC = fdot2_(bch2(wv.z), bch2(hv), aC); aD = fdot2_(bch2(wv.w), bch2(hv), aD); } }

// ---------------- weight repack: fp32 Wh[256][1024] -> packed f16x2 layout ----------------
__global__ void prep_wh_kernel(const float* __restrict__ Wh, uint32_t* __restrict__ wbuf) {
    int idx = blockIdx.x * 256 + threadIdx.x;  // 131072 total (512 blocks)
    int kp = idx >> 10, col = idx & 1023;
    union { _Float16 f[2]; uint32_t u; } p;
    p.f[0] = (_Float16)Wh[(2 * kp) * 1024 + col];
    p.f[1] = (_Float16)Wh[(2 * kp + 1) * 1024 + col];
    if (kp < 112) wbuf[((kp >> 2) * 1024 + col) * 4 + (kp & 3)] = p.u;
    else if (kp == 112) wbuf[W1_OFF + col] = p.u;
    else wbuf[WLDS_OFF + ((kp - 113) * 256 + (col & 255)) * 4 + (col >> 8)] = p.u;
}

// ---------------- encoder LSTM: 256 thr, pinned 1 wave/EU -> 512-VGPR budget ----------------
__global__ __launch_bounds__(256, 1) __attribute__((amdgpu_waves_per_eu(1, 1)))
void lstm_enc2_kernel(const uint32_t* __restrict__ wbuf, const float* __restrict__ xp, int T,
                      float* __restrict__ h_out, float* __restrict__ c_out) {
    __shared__ uint32_t wlds_s[N_KLDS * 1024];   // 60 KiB
    __shared__ uint32_t h_pk[2][128];            // h as f16x2, parity double-buffered
    int j = threadIdx.x;
    int colA = j, colB = j + 256, colC = j + 512, colD = j + 768;
    const uint4* w4 = (const uint4*)wbuf;
    Q28(DECLW)
    Q28(LOADW)
    uint32_t w1A = wbuf[W1_OFF + colA], w1B = wbuf[W1_OFF + colB];
    uint32_t w1C = wbuf[W1_OFF + colC], w1D = wbuf[W1_OFF + colD];
    for (int i = j; i < N_KLDS * 1024; i += 256) wlds_s[i] = wbuf[WLDS_OFF + i];
    if (j < 128) h_pk[0][j] = 0;
    float c = 0.f, h = 0.f;
    __syncthreads();
    int cur = 0;
    for (int t = 0; t < T; ++t) {
        const uint32_t* hp = &h_pk[cur][0];
        DOTS_ALL()
        float zi = aA + xp[t * 1024 + j];
        float zf = aB + xp[t * 1024 + j + 256];
        float zg = aC + xp[t * 1024 + j + 512];
        float zo = aD + xp[t * 1024 + j + 768];
        c = sigmoidf_(zf) * c + sigmoidf_(zi) * tanhf_(zg);
        h = sigmoidf_(zo) * tanhf_(c);
        ((_Float16*)&h_pk[cur ^ 1][0])[j] = (_Float16)h;
        __syncthreads();
        cur ^= 1;
    }
    h_out[j] = h;
    c_out[j] = c;
}

// ---------------- decoder chain with fixed-point fast-forward ----------------
__global__ __launch_bounds__(256, 1) __attribute__((amdgpu_waves_per_eu(1, 1)))
void lstm_dec2_kernel(const uint32_t* __restrict__ wbuf, const float* __restrict__ a01,
                      const int* __restrict__ tok, const float* __restrict__ h0,
                      const float* __restrict__ c0, __hip_bfloat16* __restrict__ hist) {
    __shared__ uint32_t wlds_s[N_KLDS * 1024];
    __shared__ uint32_t h_pk[2][128];
    __shared__ int flagv[2][4];
    int j = threadIdx.x;
    int colA = j, colB = j + 256, colC = j + 512, colD = j + 768;
    const uint4* w4 = (const uint4*)wbuf;
    Q28(DECLW)
    Q28(LOADW)
    uint32_t w1A = wbuf[W1_OFF + colA], w1B = wbuf[W1_OFF + colB];
    uint32_t w1C = wbuf[W1_OFF + colC], w1D = wbuf[W1_OFF + colD];
    for (int i = j; i < N_KLDS * 1024; i += 256) wlds_s[i] = wbuf[WLDS_OFF + i];
    float a0A = a01[colA], a0B = a01[colB], a0C = a01[colC], a0D = a01[colD];
    float a1A = a01[1024 + colA], a1B = a01[1024 + colB];
    float a1C = a01[1024 + colC], a1D = a01[1024 + colD];
    float h = h0[j], c = c0[j];
    ((_Float16*)&h_pk[0][0])[j] = (_Float16)h;
    __syncthreads();
    int cur = 0;
    bool prev_a0 = false, stat = false;
    int step = 0;
#pragma unroll 1
    for (int l = 0; l < 299; ++l) {
        int tk = tok[l];
        int v = 0;
        while (v < 128) {
            if (stat && v != tk) {
                // state stationary under a0 input: fast-forward to next perturbation
                int nxt = (v < tk) ? tk : 128;
                __hip_bfloat16 hb = __float2bfloat16(h);
                for (int s = v; s < nxt; ++s)
                    hist[(size_t)(step + (s - v)) * 256 + j] = hb;
                step += nxt - v;
                v = nxt;
                continue;
            }
            bool isa1 = (v == tk);
            const uint32_t* hp = &h_pk[cur][0];
            DOTS_ALL()
            float zi = aA + (isa1 ? a1A : a0A);
            float zf = aB + (isa1 ? a1B : a0B);
            float zg = aC + (isa1 ? a1C : a0C);
            float zo = aD + (isa1 ? a1D : a0D);
            float cn = sigmoidf_(zf) * c + sigmoidf_(zi) * tanhf_(zg);
            float hn = sigmoidf_(zo) * tanhf_(cn);
            bool ok = (fabsf(hn - h) <= 1e-6f) && (fabsf(cn - c) <= 1e-6f) && !isa1 && prev_a0;
            unsigned long long bal = __ballot(ok ? 1 : 0);
            if ((j & 63) == 0) flagv[cur][j >> 6] = (bal == ~0ull) ? 1 : 0;
            h = hn;
            c = cn;
            hist[(size_t)step * 256 + j] = __float2bfloat16(h);
            ((_Float16*)&h_pk[cur ^ 1][0])[j] = (_Float16)h;
            __syncthreads();
            stat = flagv[cur][0] && flagv[cur][1] && flagv[cur][2] && flagv[cur][3];
            cur ^= 1;
            prev_a0 = !isa1;
            ++step;
            ++v;
        }
    }
}

// ---------------- tok extraction ----------------
__global__ void tok_kernel(const float* __restrict__ din, int* __restrict__ tok) {
    int l = blockIdx.x * 64 + threadIdx.x;
    if (l >= 299) return;
    int t = 0;
    for (int v = 0; v < 128; ++v)
        if (din[l * 128 + v] > 0.5f) t = v;
    tok[l] = t;
}

// ---------------- STFT conv1 (3x3x1->256) + relu + 2x2 maxpool ----------------
__global__ void stft_conv1_kernel(const float* __restrict__ in, const float* __restrict__ w,
                                  const float* __restrict__ b, float* __restrict__ out) {
    int c = threadIdx.x;
    int blk = blockIdx.x;
    int pw = blk % 255, ph = blk / 255;
    int h0 = 2 * ph, w0 = 2 * pw;
    float pin[4][4];
#pragma unroll
    for (int r = 0; r < 4; ++r)
#pragma unroll
        for (int s = 0; s < 4; ++s) pin[r][s] = in[(h0 + r) * 513 + (w0 + s)];
    float acc[2][2] = {};
#pragma unroll
    for (int dh = 0; dh < 3; ++dh)
#pragma unroll
        for (int dw = 0; dw < 3; ++dw) {
            float wv = w[(dh * 3 + dw) * 256 + c];
            acc[0][0] += pin[dh][dw] * wv;
            acc[0][1] += pin[dh][dw + 1] * wv;
            acc[1][0] += pin[dh + 1][dw] * wv;
            acc[1][1] += pin[dh + 1][dw + 1] * wv;
        }
    float m = fmaxf(fmaxf(acc[0][0], acc[0][1]), fmaxf(acc[1][0], acc[1][1]));
    out[(ph * 255 + pw) * 256 + c] = fmaxf(m + b[c], 0.f);
}

// ---------------- STFT conv2 (3x3x256->256) + relu + 2x2 maxpool ----------------
__global__ void stft_conv2_kernel(const float* __restrict__ P1, const float* __restrict__ w,
                                  const float* __restrict__ b, float* __restrict__ out) {
    __shared__ float patch[4 * 8 * 256];
    int c = threadIdx.x;
    int blk = blockIdx.x;
    int pwg = blk % 42, ph = blk / 42;
    int pw0 = pwg * 3;
    int r0 = 2 * ph, c0 = 2 * pw0;
    for (int i = c; i < 4 * 8 * 256; i += 256) {
        int ci = i & 255;
        int t = i >> 8;
        int cc = t & 7, r = t >> 3;
        patch[i] = P1[((r0 + r) * 255 + (c0 + cc)) * 256 + ci];
    }
    __syncthreads();
    float acc[3][2][2] = {};
    for (int dh = 0; dh < 3; ++dh) {
        for (int ci = 0; ci < 256; ++ci) {
            float p0[8], p1[8];
#pragma unroll
            for (int x = 0; x < 8; ++x) {
                p0[x] = patch[(dh * 8 + x) * 256 + ci];
                p1[x] = patch[((dh + 1) * 8 + x) * 256 + ci];
            }
#pragma unroll
            for (int dw = 0; dw < 3; ++dw) {
                float wv = w[((dh * 3 + dw) * 256 + ci) * 256 + c];
#pragma unroll
                for (int o = 0; o < 3; ++o)
#pragma unroll
                    for (int s = 0; s < 2; ++s) {
                        acc[o][0][s] += p0[2 * o + s + dw] * wv;
                        acc[o][1][s] += p1[2 * o + s + dw] * wv;
                    }
            }
        }
    }
    float bv = b[c];
#pragma unroll
    for (int o = 0; o < 3; ++o) {
        float m = fmaxf(fmaxf(acc[o][0][0], acc[o][0][1]), fmaxf(acc[o][1][0], acc[o][1][1]));
        out[(ph * 126 + (pw0 + o)) * 256 + c] = fmaxf(m + bv, 0.f);
    }
}

// ---------------- STFT input projection: X[14,32256] @ Wi[32256,1024], split-K ----------------
__global__ void xprojS_partial_kernel(const float* __restrict__ X, const float* __restrict__ Wi,
                                      float* __restrict__ part) {
    __shared__ float xbuf[14 * 504];
    int tid = threadIdx.x;
    int kc = blockIdx.x & 63;
    int cb = blockIdx.x >> 6;
    int col = cb * 256 + tid;
    int k0 = kc * 504;
    for (int i = tid; i < 14 * 504; i += 256) {
        int t = i / 504;
        int kk = i - t * 504;
        xbuf[i] = X[t * 32256 + k0 + kk];
    }
    __syncthreads();
    float acc[14] = {};
    for (int kk = 0; kk < 504; ++kk) {
        float wv = Wi[(size_t)(k0 + kk) * 1024 + col];
#pragma unroll
        for (int t = 0; t < 14; ++t) acc[t] += xbuf[t * 504 + kk] * wv;
    }
#pragma unroll
    for (int t = 0; t < 14; ++t) part[(kc * 14 + t) * 1024 + col] = acc[t];
}

__global__ void xprojS_reduce_kernel(const float* __restrict__ part, const float* __restrict__ bias,
                                     float* __restrict__ xp) {
    int idx = blockIdx.x * 256 + threadIdx.x;  // < 14*1024
    int t = idx >> 10, col = idx & 1023;
    float s = bias[col];
    for (int kc = 0; kc < 64; ++kc) s += part[(kc * 14 + t) * 1024 + col];
    xp[idx] = s;
}

// ---------------- wave conv1 (k=3, 1024->256) + relu + pool2 ----------------
__global__ void wave_conv1_kernel(const float* __restrict__ in, const float* __restrict__ w,
                                  const float* __restrict__ b, float* __restrict__ out) {
    __shared__ float patch[4 * 1024];
    int c = threadIdx.x, t = blockIdx.x;
    for (int i = c; i < 4 * 1024; i += 256) patch[i] = in[(2 * t) * 1024 + i];
    __syncthreads();
    float acc0 = 0.f, acc1 = 0.f;
    for (int dt = 0; dt < 3; ++dt)
        for (int ci = 0; ci < 1024; ++ci) {
            float wv = w[(dt * 1024 + ci) * 256 + c];
            acc0 += patch[dt * 1024 + ci] * wv;
            acc1 += patch[(dt + 1) * 1024 + ci] * wv;
        }
    out[t * 256 + c] = fmaxf(fmaxf(acc0, acc1) + b[c], 0.f);
}

// ---------------- wave conv2 (k=3, 256->256) + relu + pool2 ----------------
__global__ void wave_conv2_kernel(const float* __restrict__ in, const float* __restrict__ w,
                                  const float* __restrict__ b, float* __restrict__ out) {
    __shared__ float patch[4 * 256];
    int c = threadIdx.x, t = blockIdx.x;
    for (int i = c; i < 4 * 256; i += 256) patch[i] = in[(2 * t) * 256 + i];
    __syncthreads();
    float acc0 = 0.f, acc1 = 0.f;
    for (int dt = 0; dt < 3; ++dt)
        for (int ci = 0; ci < 256; ++ci) {
            float wv = w[(dt * 256 + ci) * 256 + c];
            acc0 += patch[dt * 256 + ci] * wv;
            acc1 += patch[(dt + 1) * 256 + ci] * wv;
        }
    out[t * 256 + c] = fmaxf(fmaxf(acc0, acc1) + b[c], 0.f);
}

// ---------------- wave input projection X[62,256] @ Wi[256,1024] + b ----------------
__global__ void xprojW_kernel(const float* __restrict__ X, const float* __restrict__ Wi,
                              const float* __restrict__ bias, float* __restrict__ xp) {
    int idx = blockIdx.x * 256 + threadIdx.x;  // 62*1024
    int t = idx >> 10, col = idx & 1023;
    float s = bias[col];
    for (int k = 0; k < 256; ++k) s += X[t * 256 + k] * Wi[k * 1024 + col];
    xp[idx] = s;
}

// ---------------- state reducers ----------------
__global__ void reduce_state_kernel(const float* __restrict__ sh, const float* __restrict__ sc,
                                    const float* __restrict__ wh, const float* __restrict__ wc,
                                    const float* __restrict__ rhw, const float* __restrict__ rhb,
                                    const float* __restrict__ rcw, const float* __restrict__ rcb,
                                    float* __restrict__ h0, float* __restrict__ c0) {
    int m = threadIdx.x;  // 256
    float ah = rhb[m], ac = rcb[m];
    for (int k = 0; k < 256; ++k) {
        ah += sh[k] * rhw[k * 256 + m];
        ac += sc[k] * rcw[k * 256 + m];
    }
    for (int k = 0; k < 256; ++k) {
        ah += wh[k] * rhw[(256 + k) * 256 + m];
        ac += wc[k] * rcw[(256 + k) * 256 + m];
    }
    h0[m] = ah;
    c0[m] = ac;
}

// ---------------- a0/a1 = emb[s] @ d_Wi + d_b ----------------
__global__ void a01_kernel(const float* __restrict__ emb, const float* __restrict__ Wi,
                           const float* __restrict__ bias, float* __restrict__ a01) {
    int idx = blockIdx.x * 256 + threadIdx.x;  // 2048
    int s = idx >> 10, j = idx & 1023;
    float acc = bias[j];
    for (int k = 0; k < 256; ++k) acc += emb[s * 256 + k] * Wi[k * 1024 + j];
    a01[idx] = acc;
}

// ---------------- projection + softmax epilogue: 4 rows/block, 256 threads ----------------
__global__ __launch_bounds__(256) void proj_softmax_kernel(const __hip_bfloat16* __restrict__ hh,
                                                           const float* __restrict__ Wo,
                                                           const float* __restrict__ bo,
                                                           float* __restrict__ out) {
    __shared__ float hrows[4][256];
    __shared__ float llds[4][128];
    int tid = threadIdx.x;
    int rbase = blockIdx.x * 4;
    for (int i = tid; i < 1024; i += 256)
        hrows[i >> 8][i & 255] = __bfloat162float(hh[(size_t)rbase * 256 + i]);
    __syncthreads();
    int w = tid & 127, half = tid >> 7;
    int k0 = half * 128;
    float acc[4] = {};
    for (int k = 0; k < 128; ++k) {
        float wv = Wo[(k0 + k) * 128 + w];
#pragma unroll
        for (int r = 0; r < 4; ++r) acc[r] += hrows[r][k0 + k] * wv;
    }
    if (half == 0) {
#pragma unroll
        for (int r = 0; r < 4; ++r) llds[r][w] = acc[r] + bo[w];
    }
    __syncthreads();
    if (half == 1) {
#pragma unroll
        for (int r = 0; r < 4; ++r) llds[r][w] += acc[r];
    }
    __syncthreads();
    int rr = tid >> 6, lane = tid & 63;
    float x0 = llds[rr][lane], x1 = llds[rr][lane + 64];
    float mx = fmaxf(x0, x1);
    for (int off = 32; off > 0; off >>= 1) mx = fmaxf(mx, __shfl_xor(mx, off));
    float e0 = __expf(x0 - mx), e1 = __expf(x1 - mx);
    float sm = e0 + e1;
    for (int off = 32; off > 0; off >>= 1) sm += __shfl_xor(sm, off);
    float inv = 1.f / sm;
    int row = rbase + rr;
    int l = row >> 7, v = row & 127;
    float* op = out + ((size_t)v * 300 + l) * 128;
    op[lane] = e0 * inv;
    op[lane + 64] = e1 * inv;
}

// ---------------- zero last time slot l=299 ----------------
__global__ void zero_tail_kernel(float* __restrict__ out) {
    int idx = blockIdx.x * 256 + threadIdx.x;  // 128*128
    int v = idx >> 7, w = idx & 127;
    out[((size_t)v * 300 + 299) * 128 + w] = 0.f;
}

extern "C" void kernel_launch(void* const* d_in, const int* in_sizes, int n_in, void* d_out,
                              int out_size, void* d_ws, size_t ws_size, hipStream_t stream) {
    const float* stft = (const float*)d_in[0];
    const float* wave = (const float*)d_in[1];
    const float* din = (const float*)d_in[2];
    const float* s_cw1 = (const float*)d_in[3];
    const float* s_cb1 = (const float*)d_in[4];
    const float* s_cw2 = (const float*)d_in[5];
    const float* s_cb2 = (const float*)d_in[6];
    const float* s_Wi = (const float*)d_in[7];
    const float* s_Wh = (const float*)d_in[8];
    const float* s_b = (const float*)d_in[9];
    const float* w_cw1 = (const float*)d_in[10];
    const float* w_cb1 = (const float*)d_in[11];
    const float* w_cw2 = (const float*)d_in[12];
    const float* w_cb2 = (const float*)d_in[13];
    const float* w_Wi = (const float*)d_in[14];
    const float* w_Wh = (const float*)d_in[15];
    const float* w_b = (const float*)d_in[16];
    const float* rh_w = (const float*)d_in[17];
    const float* rh_b = (const float*)d_in[18];
    const float* rc_w = (const float*)d_in[19];
    const float* rc_b = (const float*)d_in[20];
    const float* emb = (const float*)d_in[21];
    const float* d_Wi = (const float*)d_in[22];
    const float* d_Wh = (const float*)d_in[23];
    const float* d_b = (const float*)d_in[24];
    const float* out_w = (const float*)d_in[25];
    const float* out_b = (const float*)d_in[26];
    float* out = (float*)d_out;
    float* ws = (float*)d_ws;

    // workspace layout (float offsets)
    const size_t off_P1s = 0;                         // 31*255*256 = 2023680 (reused for packed weights after conv2)
    const size_t off_P2s = off_P1s + 2023680;         // 14*126*256 = 451584
    const size_t off_partS = off_P2s + 451584;        // 64*14*1024 = 917504
    const size_t off_P1w = off_partS + 917504;        // 127*256 = 32512
    const size_t off_P2w = off_P1w + 32512;           // 62*256 = 15872
    const size_t off_xprojS = off_P2w + 15872;        // 14*1024
    const size_t off_xprojW = off_xprojS + 14336;     // 62*1024
    const size_t off_sh = off_xprojW + 63488;         // 4*256 states
    const size_t off_sc = off_sh + 256;
    const size_t off_wh = off_sc + 256;
    const size_t off_wc = off_wh + 256;
    const size_t off_h0 = off_wc + 256;
    const size_t off_c0 = off_h0 + 256;
    const size_t off_a01 = off_c0 + 256;              // 2048
    const size_t off_tok = off_a01 + 2048;            // 299 ints (512 slots)
    const size_t off_hh = off_tok + 512;              // bf16 region: 38272*256 bf16
    __hip_bfloat16* h_hist = (__hip_bfloat16*)(ws + off_hh);
    int* tok = (int*)(ws + off_tok);
    // packed f16 weights overlay the P1s region (free after stft_conv2): 3 x 131072 dwords
    uint32_t* wrS = (uint32_t*)(ws + off_P1s);
    uint32_t* wrW = wrS + 131072;
    uint32_t* wrD = wrW + 131072;

    tok_kernel<<<5, 64, 0, stream>>>(din, tok);

    // STFT conv pipeline (P1s in use until stft_conv2 completes)
    stft_conv1_kernel<<<31 * 255, 256, 0, stream>>>(stft, s_cw1, s_cb1, ws + off_P1s);
    stft_conv2_kernel<<<14 * 42, 256, 0, stream>>>(ws + off_P1s, s_cw2, s_cb2, ws + off_P2s);

    // repack all three Wh matrices into f16x2 layout (P1s region now free)
    prep_wh_kernel<<<512, 256, 0, stream>>>(s_Wh, wrS);
    prep_wh_kernel<<<512, 256, 0, stream>>>(w_Wh, wrW);
    prep_wh_kernel<<<512, 256, 0, stream>>>(d_Wh, wrD);

    xprojS_partial_kernel<<<256, 256, 0, stream>>>(ws + off_P2s, s_Wi, ws + off_partS);
    xprojS_reduce_kernel<<<56, 256, 0, stream>>>(ws + off_partS, s_b, ws + off_xprojS);
    lstm_enc2_kernel<<<1, 256, 0, stream>>>(wrS, ws + off_xprojS, 14, ws + off_sh, ws + off_sc);

    // waveform branch
    wave_conv1_kernel<<<127, 256, 0, stream>>>(wave, w_cw1, w_cb1, ws + off_P1w);
    wave_conv2_kernel<<<62, 256, 0, stream>>>(ws + off_P1w, w_cw2, w_cb2, ws + off_P2w);
    xprojW_kernel<<<248, 256, 0, stream>>>(ws + off_P2w, w_Wi, w_b, ws + off_xprojW);
    lstm_enc2_kernel<<<1, 256, 0, stream>>>(wrW, ws + off_xprojW, 62, ws + off_wh, ws + off_wc);

    // reducers + decoder precompute
    reduce_state_kernel<<<1, 256, 0, stream>>>(ws + off_sh, ws + off_sc, ws + off_wh, ws + off_wc,
                                               rh_w, rh_b, rc_w, rc_b, ws + off_h0, ws + off_c0);
    a01_kernel<<<8, 256, 0, stream>>>(emb, d_Wi, d_b, ws + off_a01);

    // sequential decoder chain (critical path)
    lstm_dec2_kernel<<<1, 256, 0, stream>>>(wrD, ws + off_a01, tok, ws + off_h0, ws + off_c0,
                                            h_hist);

    // parallel epilogue
    proj_softmax_kernel<<<NSTEP / 4, 256, 0, stream>>>(h_hist, out_w, out_b, out);
    zero_tail_kernel<<<64, 256, 0, stream>>>(out);
}

// Round 5
// 8798.422 us; speedup vs baseline: 78.9919x; 10.6613x over previous
//
#include <hip/hip_runtime.h>
#include <hip/hip_bf16.h>
#include <stdint.h>

// ---------------- model dims ----------------
#define V_   128
#define L_   300
#define EU_  256
#define GU_  1024    // 4*EU
#define NSTEP (299*128)   // 38272 decoder steps

// f16x2 packed weight layout (per 256x1024 Wh matrix, 131072 dwords total).
// 512 threads, thread j owns 2 gate columns: u=j&255, hi=j>>8,
//   colA = u + hi*512 (gates i / g), colB = colA + 256 (gates f / o).
//   wr4 [26][1024][4] dwords : kp=4q+p, kp<104 (k<208) -> VGPR-resident (208 regs/thread)
//   wa  [6][512] uint4       : kp 104+4qq+{0,1}, packed (A@kp0,B@kp0,A@kp1,B@kp1) -> LDS
//   wb  [6][512] uint4       : kp 104+4qq+{2,3}, same packing -> LDS
#define N_Q      26
#define WLA_OFF  106496
#define WLB_OFF  118784
#define TOL      1e-4f

typedef _Float16 h2 __attribute__((ext_vector_type(2)));

__device__ __forceinline__ float sigmoidf_(float x) { return 1.f / (1.f + __expf(-x)); }
__device__ __forceinline__ float tanhf_(float x) { return 2.f / (1.f + __expf(-2.f * x)) - 1.f; }

#if __has_builtin(__builtin_amdgcn_fdot2)
__device__ __forceinline__ float fdot2_(h2 a, h2 b, float c) { return __builtin_amdgcn_fdot2(a, b, c, false); }
#else
__device__ __forceinline__ float fdot2_(h2 a, h2 b, float c) {
    return c + (float)a.x * (float)b.x + (float)a.y * (float)b.y;
}
#endif

__device__ __forceinline__ h2 bch2(uint32_t u) {
    union { uint32_t u; h2 h; } x; x.u = u; return x.h;
}

// straight-line named registers (R2 lesson: arrays get lowered to scratch)
#define Q26(M) M(0) M(1) M(2) M(3) M(4) M(5) M(6) M(7) M(8) M(9) M(10) M(11) M(12) \
               M(13) M(14) M(15) M(16) M(17) M(18) M(19) M(20) M(21) M(22) M(23) M(24) M(25)

#define DECLW(q) uint4 wA##q, wB##q;
#define LOADW(q) wA##q = w4[(q) * 1024 + colA]; wB##q = w4[(q) * 1024 + colB];
#define DOTQ(q) { uint4 hv = hp4[q]; \
    aA = fdot2_(bch2(wA##q.x), bch2(hv.x), aA); aB = fdot2_(bch2(wB##q.x), bch2(hv.x), aB); \
    aA = fdot2_(bch2(wA##q.y), bch2(hv.y), aA); aB = fdot2_(bch2(wB##q.y), bch2(hv.y), aB); \
    aA = fdot2_(bch2(wA##q.z), bch2(hv.z), aA); aB = fdot2_(bch2(wB##q.z), bch2(hv.z), aB); \
    aA = fdot2_(bch2(wA##q.w), bch2(hv.w), aA); aB = fdot2_(bch2(wB##q.w), bch2(hv.w), aB); }

// full k=256 dot for this thread's 2 columns -> aA, aB
#define DOTS_ALL() \
    float aA = 0.f, aB = 0.f; \
    { const uint4* hp4 = (const uint4*)hp; \
      Q26(DOTQ) \
      _Pragma("unroll") \
      for (int qq = 0; qq < 6; ++qq) { \
          uint4 hv = hp4[26 + qq]; \
          uint4 wva = wa_s[qq * 512 + j]; \
          uint4 wvb = wb_s[qq * 512 + j]; \
          aA = fdot2_(bch2(wva.x), bch2(hv.x), aA); aB = fdot2_(bch2(wva.y), bch2(hv.x), aB); \
          aA = fdot2_(bch2(wva.z), bch2(hv.y), aA); aB = fdot2_(bch2(wva.w), bch2(hv.y), aB); \
          aA = fdot2_(bch2(wvb.x), bch2(hv.z), aA); aB = fdot2_(bch2(wvb.y), bch2(hv.z), aB); \
          aA = fdot2_(bch2(wvb.z), bch2(hv.w), aA); aB = fdot2_(bch2(wvb.w), bch2(hv.w), aB); } }

// ---------------- weight repack: fp32 Wh[256][1024] -> packed f16x2 layout ----------------
__global__ void prep_wh_kernel(const float* __restrict__ Wh, uint32_t* __restrict__ wbuf) {
    int idx = blockIdx.x * 256 + threadIdx.x;  // 131072 total (512 blocks)
    int kp = idx >> 10, col = idx & 1023;
    union { _Float16 f[2]; uint32_t u; } p;
    p.f[0] = (_Float16)Wh[(2 * kp) * 1024 + col];
    p.f[1] = (_Float16)Wh[(2 * kp + 1) * 1024 + col];
    if (kp < 104) {
        wbuf[(kp >> 2) * 4096 + col * 4 + (kp & 3)] = p.u;
    } else {
        int kk = kp - 104, qq = kk >> 2, r = kk & 3;
        int half = r >> 1, pi = r & 1;
        int g = col >> 8, u = col & 255;
        int jj = u + (g >> 1) * 256, ab = g & 1;
        int base = half ? WLB_OFF : WLA_OFF;
        wbuf[base + (qq * 512 + jj) * 4 + pi * 2 + ab] = p.u;
    }
}

// ---------------- encoder LSTM: 512 thr x 2 cols, weights VGPR+LDS ----------------
__global__ __launch_bounds__(512, 2) __attribute__((amdgpu_waves_per_eu(2, 2)))
void lstm_enc3_kernel(const uint32_t* __restrict__ wbuf, const float* __restrict__ xp, int T,
                      float* __restrict__ h_out, float* __restrict__ c_out) {
    __shared__ uint4 wa_s[6 * 512];          // 48 KiB
    __shared__ uint4 wb_s[6 * 512];          // 48 KiB
    __shared__ uint32_t h_pk[2][128];        // h as f16x2, parity double-buffered
    __shared__ float zgo[256][2];
    int j = threadIdx.x;
    int u = j & 255, hi = j >> 8;
    int colA = u + hi * 512, colB = colA + 256;
    const uint4* w4 = (const uint4*)wbuf;
    Q26(DECLW)
    Q26(LOADW)
    const uint4* srcA = (const uint4*)(wbuf + WLA_OFF);
    const uint4* srcB = (const uint4*)(wbuf + WLB_OFF);
    for (int i = j; i < 3072; i += 512) { wa_s[i] = srcA[i]; wb_s[i] = srcB[i]; }
    if (j < 128) h_pk[0][j] = 0;
    float c = 0.f, h = 0.f;
    __syncthreads();
    int cur = 0;
    for (int t = 0; t < T; ++t) {
        const uint32_t* hp = &h_pk[cur][0];
        DOTS_ALL()
        float zA = aA + xp[t * 1024 + colA];
        float zB = aB + xp[t * 1024 + colB];
        if (hi) { zgo[u][0] = zA; zgo[u][1] = zB; }
        __syncthreads();
        if (!hi) {
            float zg = zgo[u][0], zo = zgo[u][1];
            c = sigmoidf_(zB) * c + sigmoidf_(zA) * tanhf_(zg);
            h = sigmoidf_(zo) * tanhf_(c);
            ((_Float16*)&h_pk[cur ^ 1][0])[u] = (_Float16)h;
        }
        __syncthreads();
        cur ^= 1;
    }
    if (!hi) { h_out[u] = h; c_out[u] = c; }
}

// ---------------- decoder chain with fixed-point fast-forward ----------------
__global__ __launch_bounds__(512, 2) __attribute__((amdgpu_waves_per_eu(2, 2)))
void lstm_dec3_kernel(const uint32_t* __restrict__ wbuf, const float* __restrict__ a01,
                      const int* __restrict__ tok, const float* __restrict__ h0,
                      const float* __restrict__ c0, __hip_bfloat16* __restrict__ hist) {
    __shared__ uint4 wa_s[6 * 512];
    __shared__ uint4 wb_s[6 * 512];
    __shared__ uint32_t h_pk[2][128];
    __shared__ float zgo[256][2];
    __shared__ int flagv[2][4];
    int j = threadIdx.x;
    int u = j & 255, hi = j >> 8;
    int colA = u + hi * 512, colB = colA + 256;
    const uint4* w4 = (const uint4*)wbuf;
    Q26(DECLW)
    Q26(LOADW)
    const uint4* srcA = (const uint4*)(wbuf + WLA_OFF);
    const uint4* srcB = (const uint4*)(wbuf + WLB_OFF);
    for (int i = j; i < 3072; i += 512) { wa_s[i] = srcA[i]; wb_s[i] = srcB[i]; }
    float a0A = a01[colA], a0B = a01[colB];
    float a1A = a01[1024 + colA], a1B = a01[1024 + colB];
    float h = 0.f, c = 0.f;
    if (!hi) {
        h = h0[u];
        c = c0[u];
        ((_Float16*)&h_pk[0][0])[u] = (_Float16)h;
    }
    __syncthreads();
    int cur = 0;
    bool prev_a0 = false, stat = false;
    int step = 0;
#pragma unroll 1
    for (int l = 0; l < 299; ++l) {
        int tk = tok[l];
        int v = 0;
        while (v < 128) {
            if (stat && v != tk) {
                // state stationary under a0 input: fast-forward to next perturbation
                int nxt = (v < tk) ? tk : 128;
                if (!hi) {
                    __hip_bfloat16 hb = __float2bfloat16(h);
                    for (int s = v; s < nxt; ++s)
                        hist[(size_t)(step + (s - v)) * 256 + u] = hb;
                }
                step += nxt - v;
                v = nxt;
                continue;
            }
            bool isa1 = (v == tk);
            const uint32_t* hp = &h_pk[cur][0];
            DOTS_ALL()
            float zA = aA + (isa1 ? a1A : a0A);
            float zB = aB + (isa1 ? a1B : a0B);
            if (hi) { zgo[u][0] = zA; zgo[u][1] = zB; }
            __syncthreads();
            if (!hi) {
                float zg = zgo[u][0], zo = zgo[u][1];
                float cn = sigmoidf_(zB) * c + sigmoidf_(zA) * tanhf_(zg);
                float hn = sigmoidf_(zo) * tanhf_(cn);
                bool ok = (fabsf(hn - h) <= TOL) && (fabsf(cn - c) <= TOL) && !isa1 && prev_a0;
                unsigned long long bal = __ballot(ok ? 1 : 0);
                if ((j & 63) == 0) flagv[cur][j >> 6] = (bal == ~0ull) ? 1 : 0;
                h = hn;
                c = cn;
                hist[(size_t)step * 256 + u] = __float2bfloat16(h);
                ((_Float16*)&h_pk[cur ^ 1][0])[u] = (_Float16)h;
            }
            __syncthreads();
            stat = flagv[cur][0] && flagv[cur][1] && flagv[cur][2] && flagv[cur][3];
            cur ^= 1;
            prev_a0 = !isa1;
            ++step;
            ++v;
        }
    }
}

// ---------------- tok extraction ----------------
__global__ void tok_kernel(const float* __restrict__ din, int* __restrict__ tok) {
    int l = blockIdx.x * 64 + threadIdx.x;
    if (l >= 299) return;
    int t = 0;
    for (int v = 0; v < 128; ++v)
        if (din[l * 128 + v] > 0.5f) t = v;
    tok[l] = t;
}

// ---------------- STFT conv1 (3x3x1->256) + relu + 2x2 maxpool ----------------
__global__ void stft_conv1_kernel(const float* __restrict__ in, const float* __restrict__ w,
                                  const float* __restrict__ b, float* __restrict__ out) {
    int c = threadIdx.x;
    int blk = blockIdx.x;
    int pw = blk % 255, ph = blk / 255;
    int h0 = 2 * ph, w0 = 2 * pw;
    float pin[4][4];
#pragma unroll
    for (int r = 0; r < 4; ++r)
#pragma unroll
        for (int s = 0; s < 4; ++s) pin[r][s] = in[(h0 + r) * 513 + (w0 + s)];
    float acc[2][2] = {};
#pragma unroll
    for (int dh = 0; dh < 3; ++dh)
#pragma unroll
        for (int dw = 0; dw < 3; ++dw) {
            float wv = w[(dh * 3 + dw) * 256 + c];
            acc[0][0] += pin[dh][dw] * wv;
            acc[0][1] += pin[dh][dw + 1] * wv;
            acc[1][0] += pin[dh + 1][dw] * wv;
            acc[1][1] += pin[dh + 1][dw + 1] * wv;
        }
    float m = fmaxf(fmaxf(acc[0][0], acc[0][1]), fmaxf(acc[1][0], acc[1][1]));
    out[(ph * 255 + pw) * 256 + c] = fmaxf(m + b[c], 0.f);
}

// ---------------- STFT conv2 (3x3x256->256) + relu + 2x2 maxpool ----------------
__global__ void stft_conv2_kernel(const float* __restrict__ P1, const float* __restrict__ w,
                                  const float* __restrict__ b, float* __restrict__ out) {
    __shared__ float patch[4 * 8 * 256];
    int c = threadIdx.x;
    int blk = blockIdx.x;
    int pwg = blk % 42, ph = blk / 42;
    int pw0 = pwg * 3;
    int r0 = 2 * ph, c0 = 2 * pw0;
    for (int i = c; i < 4 * 8 * 256; i += 256) {
        int ci = i & 255;
        int t = i >> 8;
        int cc = t & 7, r = t >> 3;
        patch[i] = P1[((r0 + r) * 255 + (c0 + cc)) * 256 + ci];
    }
    __syncthreads();
    float acc[3][2][2] = {};
    for (int dh = 0; dh < 3; ++dh) {
        for (int ci = 0; ci < 256; ++ci) {
            float p0[8], p1[8];
#pragma unroll
            for (int x = 0; x < 8; ++x) {
                p0[x] = patch[(dh * 8 + x) * 256 + ci];
                p1[x] = patch[((dh + 1) * 8 + x) * 256 + ci];
            }
#pragma unroll
            for (int dw = 0; dw < 3; ++dw) {
                float wv = w[((dh * 3 + dw) * 256 + ci) * 256 + c];
#pragma unroll
                for (int o = 0; o < 3; ++o)
#pragma unroll
                    for (int s = 0; s < 2; ++s) {
                        acc[o][0][s] += p0[2 * o + s + dw] * wv;
                        acc[o][1][s] += p1[2 * o + s + dw] * wv;
                    }
            }
        }
    }
    float bv = b[c];
#pragma unroll
    for (int o = 0; o < 3; ++o) {
        float m = fmaxf(fmaxf(acc[o][0][0], acc[o][0][1]), fmaxf(acc[o][1][0], acc[o][1][1]));
        out[(ph * 126 + (pw0 + o)) * 256 + c] = fmaxf(m + bv, 0.f);
    }
}

// ---------------- STFT input projection: X[14,32256] @ Wi[32256,1024], split-K ----------------
__global__ void xprojS_partial_kernel(const float* __restrict__ X, const float* __restrict__ Wi,
                                      float* __restrict__ part) {
    __shared__ float xbuf[14 * 504];
    int tid = threadIdx.x;
    int kc = blockIdx.x & 63;
    int cb = blockIdx.x >> 6;
    int col = cb * 256 + tid;
    int k0 = kc * 504;
    for (int i = tid; i < 14 * 504; i += 256) {
        int t = i / 504;
        int kk = i - t * 504;
        xbuf[i] = X[t * 32256 + k0 + kk];
    }
    __syncthreads();
    float acc[14] = {};
    for (int kk = 0; kk < 504; ++kk) {
        float wv = Wi[(size_t)(k0 + kk) * 1024 + col];
#pragma unroll
        for (int t = 0; t < 14; ++t) acc[t] += xbuf[t * 504 + kk] * wv;
    }
#pragma unroll
    for (int t = 0; t < 14; ++t) part[(kc * 14 + t) * 1024 + col] = acc[t];
}

__global__ void xprojS_reduce_kernel(const float* __restrict__ part, const float* __restrict__ bias,
                                     float* __restrict__ xp) {
    int idx = blockIdx.x * 256 + threadIdx.x;  // < 14*1024
    int t = idx >> 10, col = idx & 1023;
    float s = bias[col];
    for (int kc = 0; kc < 64; ++kc) s += part[(kc * 14 + t) * 1024 + col];
    xp[idx] = s;
}

// ---------------- wave conv1 (k=3, 1024->256) + relu + pool2 ----------------
__global__ void wave_conv1_kernel(const float* __restrict__ in, const float* __restrict__ w,
                                  const float* __restrict__ b, float* __restrict__ out) {
    __shared__ float patch[4 * 1024];
    int c = threadIdx.x, t = blockIdx.x;
    for (int i = c; i < 4 * 1024; i += 256) patch[i] = in[(2 * t) * 1024 + i];
    __syncthreads();
    float acc0 = 0.f, acc1 = 0.f;
    for (int dt = 0; dt < 3; ++dt)
        for (int ci = 0; ci < 1024; ++ci) {
            float wv = w[(dt * 1024 + ci) * 256 + c];
            acc0 += patch[dt * 1024 + ci] * wv;
            acc1 += patch[(dt + 1) * 1024 + ci] * wv;
        }
    out[t * 256 + c] = fmaxf(fmaxf(acc0, acc1) + b[c], 0.f);
}

// ---------------- wave conv2 (k=3, 256->256) + relu + pool2 ----------------
__global__ void wave_conv2_kernel(const float* __restrict__ in, const float* __restrict__ w,
                                  const float* __restrict__ b, float* __restrict__ out) {
    __shared__ float patch[4 * 256];
    int c = threadIdx.x, t = blockIdx.x;
    for (int i = c; i < 4 * 256; i += 256) patch[i] = in[(2 * t) * 256 + i];
    __syncthreads();
    float acc0 = 0.f, acc1 = 0.f;
    for (int dt = 0; dt < 3; ++dt)
        for (int ci = 0; ci < 256; ++ci) {
            float wv = w[(dt * 256 + ci) * 256 + c];
            acc0 += patch[dt * 256 + ci] * wv;
            acc1 += patch[(dt + 1) * 256 + ci] * wv;
        }
    out[t * 256 + c] = fmaxf(fmaxf(acc0, acc1) + b[c], 0.f);
}

// ---------------- wave input projection X[62,256] @ Wi[256,1024] + b ----------------
__global__ void xprojW_kernel(const float* __restrict__ X, const float* __restrict__ Wi,
                              const float* __restrict__ bias, float* __restrict__ xp) {
    int idx = blockIdx.x * 256 + threadIdx.x;  // 62*1024
    int t = idx >> 10, col = idx & 1023;
    float s = bias[col];
    for (int k = 0; k < 256; ++k) s += X[t * 256 + k] * Wi[k * 1024 + col];
    xp[idx] = s;
}

// ---------------- state reducers ----------------
__global__ void reduce_state_kernel(const float* __restrict__ sh, const float* __restrict__ sc,
                                    const float* __restrict__ wh, const float* __restrict__ wc,
                                    const float* __restrict__ rhw, const float* __restrict__ rhb,
                                    const float* __restrict__ rcw, const float* __restrict__ rcb,
                                    float* __restrict__ h0, float* __restrict__ c0) {
    int m = threadIdx.x;  // 256
    float ah = rhb[m], ac = rcb[m];
    for (int k = 0; k < 256; ++k) {
        ah += sh[k] * rhw[k * 256 + m];
        ac += sc[k] * rcw[k * 256 + m];
    }
    for (int k = 0; k < 256; ++k) {
        ah += wh[k] * rhw[(256 + k) * 256 + m];
        ac += wc[k] * rcw[(256 + k) * 256 + m];
    }
    h0[m] = ah;
    c0[m] = ac;
}

// ---------------- a0/a1 = emb[s] @ d_Wi + d_b ----------------
__global__ void a01_kernel(const float* __restrict__ emb, const float* __restrict__ Wi,
                           const float* __restrict__ bias, float* __restrict__ a01) {
    int idx = blockIdx.x * 256 + threadIdx.x;  // 2048
    int s = idx >> 10, j = idx & 1023;
    float acc = bias[j];
    for (int k = 0; k < 256; ++k) acc += emb[s * 256 + k] * Wi[k * 1024 + j];
    a01[idx] = acc;
}

// ---------------- projection + softmax epilogue: 4 rows/block, 256 threads ----------------
__global__ __launch_bounds__(256) void proj_softmax_kernel(const __hip_bfloat16* __restrict__ hh,
                                                           const float* __restrict__ Wo,
                                                           const float* __restrict__ bo,
                                                           float* __restrict__ out) {
    __shared__ float hrows[4][256];
    __shared__ float llds[4][128];
    int tid = threadIdx.x;
    int rbase = blockIdx.x * 4;
    for (int i = tid; i < 1024; i += 256)
        hrows[i >> 8][i & 255] = __bfloat162float(hh[(size_t)rbase * 256 + i]);
    __syncthreads();
    int w = tid & 127, half = tid >> 7;
    int k0 = half * 128;
    float acc[4] = {};
    for (int k = 0; k < 128; ++k) {
        float wv = Wo[(k0 + k) * 128 + w];
#pragma unroll
        for (int r = 0; r < 4; ++r) acc[r] += hrows[r][k0 + k] * wv;
    }
    if (half == 0) {
#pragma unroll
        for (int r = 0; r < 4; ++r) llds[r][w] = acc[r] + bo[w];
    }
    __syncthreads();
    if (half == 1) {
#pragma unroll
        for (int r = 0; r < 4; ++r) llds[r][w] += acc[r];
    }
    __syncthreads();
    int rr = tid >> 6, lane = tid & 63;
    float x0 = llds[rr][lane], x1 = llds[rr][lane + 64];
    float mx = fmaxf(x0, x1);
    for (int off = 32; off > 0; off >>= 1) mx = fmaxf(mx, __shfl_xor(mx, off));
    float e0 = __expf(x0 - mx), e1 = __expf(x1 - mx);
    float sm = e0 + e1;
    for (int off = 32; off > 0; off >>= 1) sm += __shfl_xor(sm, off);
    float inv = 1.f / sm;
    int row = rbase + rr;
    int l = row >> 7, v = row & 127;
    float* op = out + ((size_t)v * 300 + l) * 128;
    op[lane] = e0 * inv;
    op[lane + 64] = e1 * inv;
}

// ---------------- zero last time slot l=299 ----------------
__global__ void zero_tail_kernel(float* __restrict__ out) {
    int idx = blockIdx.x * 256 + threadIdx.x;  // 128*128
    int v = idx >> 7, w = idx & 127;
    out[((size_t)v * 300 + 299) * 128 + w] = 0.f;
}

extern "C" void kernel_launch(void* const* d_in, const int* in_sizes, int n_in, void* d_out,
                              int out_size, void* d_ws, size_t ws_size, hipStream_t stream) {
    const float* stft = (const float*)d_in[0];
    const float* wave = (const float*)d_in[1];
    const float* din = (const float*)d_in[2];
    const float* s_cw1 = (const float*)d_in[3];
    const float* s_cb1 = (const float*)d_in[4];
    const float* s_cw2 = (const float*)d_in[5];
    const float* s_cb2 = (const float*)d_in[6];
    const float* s_Wi = (const float*)d_in[7];
    const float* s_Wh = (const float*)d_in[8];
    const float* s_b = (const float*)d_in[9];
    const float* w_cw1 = (const float*)d_in[10];
    const float* w_cb1 = (const float*)d_in[11];
    const float* w_cw2 = (const float*)d_in[12];
    const float* w_cb2 = (const float*)d_in[13];
    const float* w_Wi = (const float*)d_in[14];
    const float* w_Wh = (const float*)d_in[15];
    const float* w_b = (const float*)d_in[16];
    const float* rh_w = (const float*)d_in[17];
    const float* rh_b = (const float*)d_in[18];
    const float* rc_w = (const float*)d_in[19];
    const float* rc_b = (const float*)d_in[20];
    const float* emb = (const float*)d_in[21];
    const float* d_Wi = (const float*)d_in[22];
    const float* d_Wh = (const float*)d_in[23];
    const float* d_b = (const float*)d_in[24];
    const float* out_w = (const float*)d_in[25];
    const float* out_b = (const float*)d_in[26];
    float* out = (float*)d_out;
    float* ws = (float*)d_ws;

    // workspace layout (float offsets)
    const size_t off_P1s = 0;                         // 31*255*256 = 2023680 (reused for packed weights)
    const size_t off_P2s = off_P1s + 2023680;         // 14*126*256 = 451584
    const size_t off_partS = off_P2s + 451584;        // 64*14*1024 = 917504
    const size_t off_P1w = off_partS + 917504;        // 127*256 = 32512
    const size_t off_P2w = off_P1w + 32512;           // 62*256 = 15872
    const size_t off_xprojS = off_P2w + 15872;        // 14*1024
    const size_t off_xprojW = off_xprojS + 14336;     // 62*1024
    const size_t off_sh = off_xprojW + 63488;         // 4*256 states
    const size_t off_sc = off_sh + 256;
    const size_t off_wh = off_sc + 256;
    const size_t off_wc = off_wh + 256;
    const size_t off_h0 = off_wc + 256;
    const size_t off_c0 = off_h0 + 256;
    const size_t off_a01 = off_c0 + 256;              // 2048
    const size_t off_tok = off_a01 + 2048;            // 299 ints (512 slots)
    const size_t off_hh = off_tok + 512;              // bf16 region: 38272*256 bf16
    __hip_bfloat16* h_hist = (__hip_bfloat16*)(ws + off_hh);
    int* tok = (int*)(ws + off_tok);
    // packed f16 weights overlay the P1s region (free after stft_conv2): 3 x 131072 dwords
    uint32_t* wrS = (uint32_t*)(ws + off_P1s);
    uint32_t* wrW = wrS + 131072;
    uint32_t* wrD = wrW + 131072;

    tok_kernel<<<5, 64, 0, stream>>>(din, tok);

    // STFT conv pipeline (P1s in use until stft_conv2 completes)
    stft_conv1_kernel<<<31 * 255, 256, 0, stream>>>(stft, s_cw1, s_cb1, ws + off_P1s);
    stft_conv2_kernel<<<14 * 42, 256, 0, stream>>>(ws + off_P1s, s_cw2, s_cb2, ws + off_P2s);

    // repack all three Wh matrices into f16x2 layout (P1s region now free)
    prep_wh_kernel<<<512, 256, 0, stream>>>(s_Wh, wrS);
    prep_wh_kernel<<<512, 256, 0, stream>>>(w_Wh, wrW);
    prep_wh_kernel<<<512, 256, 0, stream>>>(d_Wh, wrD);

    xprojS_partial_kernel<<<256, 256, 0, stream>>>(ws + off_P2s, s_Wi, ws + off_partS);
    xprojS_reduce_kernel<<<56, 256, 0, stream>>>(ws + off_partS, s_b, ws + off_xprojS);
    lstm_enc3_kernel<<<1, 512, 0, stream>>>(wrS, ws + off_xprojS, 14, ws + off_sh, ws + off_sc);

    // waveform branch
    wave_conv1_kernel<<<127, 256, 0, stream>>>(wave, w_cw1, w_cb1, ws + off_P1w);
    wave_conv2_kernel<<<62, 256, 0, stream>>>(ws + off_P1w, w_cw2, w_cb2, ws + off_P2w);
    xprojW_kernel<<<248, 256, 0, stream>>>(ws + off_P2w, w_Wi, w_b, ws + off_xprojW);
    lstm_enc3_kernel<<<1, 512, 0, stream>>>(wrW, ws + off_xprojW, 62, ws + off_wh, ws + off_wc);

    // reducers + decoder precompute
    reduce_state_kernel<<<1, 256, 0, stream>>>(ws + off_sh, ws + off_sc, ws + off_wh, ws + off_wc,
                                               rh_w, rh_b, rc_w, rc_b, ws + off_h0, ws + off_c0);
    a01_kernel<<<8, 256, 0, stream>>>(emb, d_Wi, d_b, ws + off_a01);

    // sequential decoder chain (critical path)
    lstm_dec3_kernel<<<1, 512, 0, stream>>>(wrD, ws + off_a01, tok, ws + off_h0, ws + off_c0,
                                            h_hist);

    // parallel epilogue
    proj_softmax_kernel<<<NSTEP / 4, 256, 0, stream>>>(h_hist, out_w, out_b, out);
    zero_tail_kernel<<<64, 256, 0, stream>>>(out);
}

// Round 6
// 2165.911 us; speedup vs baseline: 320.8829x; 4.0622x over previous
//
#include <hip/hip_runtime.h>
#include <hip/hip_bf16.h>
#include <stdint.h>

// ---------------- model dims ----------------
#define V_   128
#define L_   300
#define EU_  256
#define GU_  1024    // 4*EU
#define NSTEP (299*128)   // 38272 decoder steps

// f16x2 packed weight layout (per 256x1024 Wh matrix, 131072 dwords total).
// 512 threads, thread j owns 2 gate columns: u=j&255, hi=j>>8,
//   colA = u + hi*512 (gates i / g), colB = colA + 256 (gates f / o).
//   wr4 [26][1024][4] dwords : kp=4q+p, kp<104 (k<208) -> VGPR-resident
//   wa  [6][512] uint4       : kp 104+4qq+{0,1}, packed (A@kp0,B@kp0,A@kp1,B@kp1) -> LDS
//   wb  [6][512] uint4       : kp 104+4qq+{2,3}, same packing -> LDS
#define N_Q      26
#define WLA_OFF  106496
#define WLB_OFF  118784
#define TOL      1e-4f
#define MEMO_T   32      // max memoized trajectory length (abort build past this)

typedef _Float16 h2 __attribute__((ext_vector_type(2)));

__device__ __forceinline__ float sigmoidf_(float x) { return 1.f / (1.f + __expf(-x)); }
__device__ __forceinline__ float tanhf_(float x) { return 2.f / (1.f + __expf(-2.f * x)) - 1.f; }

#if __has_builtin(__builtin_amdgcn_fdot2)
__device__ __forceinline__ float fdot2_(h2 a, h2 b, float c) { return __builtin_amdgcn_fdot2(a, b, c, false); }
#else
__device__ __forceinline__ float fdot2_(h2 a, h2 b, float c) {
    return c + (float)a.x * (float)b.x + (float)a.y * (float)b.y;
}
#endif

__device__ __forceinline__ h2 bch2(uint32_t u) {
    union { uint32_t u; h2 h; } x; x.u = u; return x.h;
}

__device__ __forceinline__ unsigned short bf16bits_(float f) {
    union { __hip_bfloat16 b; unsigned short s; } x;
    x.b = __float2bfloat16(f);
    return x.s;
}

// f16x2 dword -> bf16x2 dword (for batched skip writes from h_pk)
__device__ __forceinline__ uint32_t f16x2_to_bf16x2_(uint32_t hw) {
    union { uint32_t u; _Float16 f[2]; } x;
    x.u = hw;
    uint32_t lo = bf16bits_((float)x.f[0]);
    uint32_t hi = bf16bits_((float)x.f[1]);
    return (hi << 16) | lo;
}

// straight-line named registers (R2 lesson: arrays get lowered to scratch)
#define Q26(M) M(0) M(1) M(2) M(3) M(4) M(5) M(6) M(7) M(8) M(9) M(10) M(11) M(12) \
               M(13) M(14) M(15) M(16) M(17) M(18) M(19) M(20) M(21) M(22) M(23) M(24) M(25)

#define DECLW(q) uint4 wA##q, wB##q;
#define LOADW(q) wA##q = w4[(q) * 1024 + colA]; wB##q = w4[(q) * 1024 + colB];
#define DOTQ(q) { uint4 hv = hp4[q]; \
    aA = fdot2_(bch2(wA##q.x), bch2(hv.x), aA); aB = fdot2_(bch2(wB##q.x), bch2(hv.x), aB); \
    aA = fdot2_(bch2(wA##q.y), bch2(hv.y), aA); aB = fdot2_(bch2(wB##q.y), bch2(hv.y), aB); \
    aA = fdot2_(bch2(wA##q.z), bch2(hv.z), aA); aB = fdot2_(bch2(wB##q.z), bch2(hv.z), aB); \
    aA = fdot2_(bch2(wA##q.w), bch2(hv.w), aA); aB = fdot2_(bch2(wB##q.w), bch2(hv.w), aB); }

// full k=256 dot for this thread's 2 columns -> aA, aB
#define DOTS_ALL() \
    float aA = 0.f, aB = 0.f; \
    { const uint4* hp4 = (const uint4*)hp; \
      Q26(DOTQ) \
      _Pragma("unroll") \
      for (int qq = 0; qq < 6; ++qq) { \
          uint4 hv = hp4[26 + qq]; \
          uint4 wva = wa_s[qq * 512 + j]; \
          uint4 wvb = wb_s[qq * 512 + j]; \
          aA = fdot2_(bch2(wva.x), bch2(hv.x), aA); aB = fdot2_(bch2(wva.y), bch2(hv.x), aB); \
          aA = fdot2_(bch2(wva.z), bch2(hv.y), aA); aB = fdot2_(bch2(wva.w), bch2(hv.y), aB); \
          aA = fdot2_(bch2(wvb.x), bch2(hv.z), aA); aB = fdot2_(bch2(wvb.y), bch2(hv.z), aB); \
          aA = fdot2_(bch2(wvb.z), bch2(hv.w), aA); aB = fdot2_(bch2(wvb.w), bch2(hv.w), aB); } }

// ---------------- weight repack: fp32 Wh[256][1024] -> packed f16x2 layout ----------------
__global__ void prep_wh_kernel(const float* __restrict__ Wh, uint32_t* __restrict__ wbuf) {
    int idx = blockIdx.x * 256 + threadIdx.x;  // 131072 total (512 blocks)
    int kp = idx >> 10, col = idx & 1023;
    union { _Float16 f[2]; uint32_t u; } p;
    p.f[0] = (_Float16)Wh[(2 * kp) * 1024 + col];
    p.f[1] = (_Float16)Wh[(2 * kp + 1) * 1024 + col];
    if (kp < 104) {
        wbuf[(kp >> 2) * 4096 + col * 4 + (kp & 3)] = p.u;
    } else {
        int kk = kp - 104, qq = kk >> 2, r = kk & 3;
        int half = r >> 1, pi = r & 1;
        int g = col >> 8, u = col & 255;
        int jj = u + (g >> 1) * 256, ab = g & 1;
        int base = half ? WLB_OFF : WLA_OFF;
        wbuf[base + (qq * 512 + jj) * 4 + pi * 2 + ab] = p.u;
    }
}

// ---------------- encoder LSTM: 512 thr x 2 cols, weights VGPR+LDS ----------------
__global__ __launch_bounds__(512, 2) __attribute__((amdgpu_waves_per_eu(2, 2)))
void lstm_enc3_kernel(const uint32_t* __restrict__ wbuf, const float* __restrict__ xp, int T,
                      float* __restrict__ h_out, float* __restrict__ c_out) {
    __shared__ uint4 wa_s[6 * 512];          // 48 KiB
    __shared__ uint4 wb_s[6 * 512];          // 48 KiB
    __shared__ uint32_t h_pk[2][128];        // h as f16x2, parity double-buffered
    __shared__ float zgo[256][2];
    int j = threadIdx.x;
    int u = j & 255, hi = j >> 8;
    int colA = u + hi * 512, colB = colA + 256;
    const uint4* w4 = (const uint4*)wbuf;
    Q26(DECLW)
    Q26(LOADW)
    const uint4* srcA = (const uint4*)(wbuf + WLA_OFF);
    const uint4* srcB = (const uint4*)(wbuf + WLB_OFF);
    for (int i = j; i < 3072; i += 512) { wa_s[i] = srcA[i]; wb_s[i] = srcB[i]; }
    if (j < 128) h_pk[0][j] = 0;
    float c = 0.f, h = 0.f;
    __syncthreads();
    int cur = 0;
    for (int t = 0; t < T; ++t) {
        const uint32_t* hp = &h_pk[cur][0];
        DOTS_ALL()
        float zA = aA + xp[t * 1024 + colA];
        float zB = aB + xp[t * 1024 + colB];
        if (hi) { zgo[u][0] = zA; zgo[u][1] = zB; }
        __syncthreads();
        if (!hi) {
            float zg = zgo[u][0], zo = zgo[u][1];
            c = sigmoidf_(zB) * c + sigmoidf_(zA) * tanhf_(zg);
            h = sigmoidf_(zo) * tanhf_(c);
            ((_Float16*)&h_pk[cur ^ 1][0])[u] = (_Float16)h;
        }
        __syncthreads();
        cur ^= 1;
    }
    if (!hi) { h_out[u] = h; c_out[u] = c; }
}

// ---------------- decoder chain: fixed-point skip + trajectory memoization ----------------
// Every perturbation (a1 at v==tk) launched from the a0 fixed point follows the SAME
// trajectory -> compute it once, memoize bf16 rows + f16 (h,c) restore states in LDS,
// replay via coalesced LDS->global copies for all later l.
__global__ __launch_bounds__(512, 2) __attribute__((amdgpu_waves_per_eu(2, 2)))
void lstm_dec4_kernel(const uint32_t* __restrict__ wbuf, const float* __restrict__ a01,
                      const int* __restrict__ tok, const float* __restrict__ h0,
                      const float* __restrict__ c0, __hip_bfloat16* __restrict__ hist) {
    __shared__ uint4 wa_s[6 * 512];
    __shared__ uint4 wb_s[6 * 512];
    __shared__ uint32_t h_pk[2][128];
    __shared__ float zgo[256][2];
    __shared__ int flagv[2][4];
    __shared__ unsigned short memo_hb[MEMO_T * 256];  // bf16 h rows (ready-to-copy)
    __shared__ uint32_t memo_st[MEMO_T * 256];        // f16 h | f16 c per (step, u)
    int j = threadIdx.x;
    int u = j & 255, hi = j >> 8;
    int colA = u + hi * 512, colB = colA + 256;
    const uint4* w4 = (const uint4*)wbuf;
    Q26(DECLW)
    Q26(LOADW)
    const uint4* srcA = (const uint4*)(wbuf + WLA_OFF);
    const uint4* srcB = (const uint4*)(wbuf + WLB_OFF);
    for (int i = j; i < 3072; i += 512) { wa_s[i] = srcA[i]; wb_s[i] = srcB[i]; }
    float a0A = a01[colA], a0B = a01[colB];
    float a1A = a01[1024 + colA], a1B = a01[1024 + colB];
    float h = 0.f, c = 0.f;
    if (!hi) {
        h = h0[u];
        c = c0[u];
        ((_Float16*)&h_pk[0][0])[u] = (_Float16)h;
    }
    __syncthreads();
    uint32_t* hist32 = (uint32_t*)hist;
    const uint32_t* memo_hb32 = (const uint32_t*)memo_hb;
    int rlane = j >> 7;       // 0..3: this thread's row phase in batched copies
    int dlane = j & 127;      // dword index within a 128-dword hist row
    int cur = 0;
    bool prev_a0 = false, stat = false;
    bool memo_valid = false, building = false;
    int bidx = 0, memo_len = 0;
    int step = 0;
#pragma unroll 1
    for (int l = 0; l < 299; ++l) {
        int tk = tok[l];
        int v = 0;
        while (v < 128) {
            if (stat && v != tk) {
                // stationary under a0: batched write of identical rows, jump ahead
                int nxt = (v < tk) ? tk : 128;
                int cnt = nxt - v;
                uint32_t mydw = f16x2_to_bf16x2_(h_pk[cur][dlane]);
                for (int r = rlane; r < cnt; r += 4)
                    hist32[(size_t)(step + r) * 128 + dlane] = mydw;
                step += cnt;
                v = nxt;
                continue;
            }
            if (v == tk && stat && memo_valid) {
                // replay memoized perturbation trajectory
                int M = (memo_len < 128 - v) ? memo_len : (128 - v);
                for (int r = rlane; r < M; r += 4)
                    hist32[(size_t)(step + r) * 128 + dlane] = memo_hb32[r * 128 + dlane];
                if (!hi) {
                    union { uint32_t w; _Float16 f[2]; } s;
                    s.w = memo_st[(M - 1) * 256 + u];
                    h = (float)s.f[0];
                    c = (float)s.f[1];
                    ((_Float16*)&h_pk[cur][0])[u] = s.f[0];
                }
                step += M;
                v += M;
                if (M == memo_len) { stat = true; prev_a0 = true; }
                else { stat = false; prev_a0 = (M > 1); }
                __syncthreads();
                continue;
            }
            // normal computed step (records memo during build)
            bool isa1 = (v == tk);
            if (isa1 && stat && !memo_valid && !building) { building = true; bidx = 0; }
            const uint32_t* hp = &h_pk[cur][0];
            DOTS_ALL()
            float zA = aA + (isa1 ? a1A : a0A);
            float zB = aB + (isa1 ? a1B : a0B);
            if (hi) { zgo[u][0] = zA; zgo[u][1] = zB; }
            __syncthreads();
            if (!hi) {
                float zg = zgo[u][0], zo = zgo[u][1];
                float cn = sigmoidf_(zB) * c + sigmoidf_(zA) * tanhf_(zg);
                float hn = sigmoidf_(zo) * tanhf_(cn);
                bool ok = (fabsf(hn - h) <= TOL) && (fabsf(cn - c) <= TOL) && !isa1 && prev_a0;
                unsigned long long bal = __ballot(ok ? 1 : 0);
                if ((j & 63) == 0) flagv[cur][j >> 6] = (bal == ~0ull) ? 1 : 0;
                h = hn;
                c = cn;
                unsigned short hb = bf16bits_(hn);
                ((unsigned short*)hist)[(size_t)step * 256 + u] = hb;
                ((_Float16*)&h_pk[cur ^ 1][0])[u] = (_Float16)hn;
                if (building) {
                    memo_hb[bidx * 256 + u] = hb;
                    union { uint32_t w; _Float16 f[2]; } s;
                    s.f[0] = (_Float16)hn;
                    s.f[1] = (_Float16)cn;
                    memo_st[bidx * 256 + u] = s.w;
                }
            }
            __syncthreads();
            stat = flagv[cur][0] && flagv[cur][1] && flagv[cur][2] && flagv[cur][3];
            cur ^= 1;
            prev_a0 = !isa1;
            ++step;
            ++v;
            if (building) {
                if (stat) { memo_len = bidx + 1; memo_valid = true; building = false; }
                else if (bidx + 1 >= MEMO_T) building = false;  // abort: too long
                else ++bidx;
            }
        }
        building = false;  // abort any build crossing an l boundary
    }
}

// ---------------- tok extraction ----------------
__global__ void tok_kernel(const float* __restrict__ din, int* __restrict__ tok) {
    int l = blockIdx.x * 64 + threadIdx.x;
    if (l >= 299) return;
    int t = 0;
    for (int v = 0; v < 128; ++v)
        if (din[l * 128 + v] > 0.5f) t = v;
    tok[l] = t;
}

// ---------------- STFT conv1 (3x3x1->256) + relu + 2x2 maxpool ----------------
__global__ void stft_conv1_kernel(const float* __restrict__ in, const float* __restrict__ w,
                                  const float* __restrict__ b, float* __restrict__ out) {
    int c = threadIdx.x;
    int blk = blockIdx.x;
    int pw = blk % 255, ph = blk / 255;
    int h0 = 2 * ph, w0 = 2 * pw;
    float pin[4][4];
#pragma unroll
    for (int r = 0; r < 4; ++r)
#pragma unroll
        for (int s = 0; s < 4; ++s) pin[r][s] = in[(h0 + r) * 513 + (w0 + s)];
    float acc[2][2] = {};
#pragma unroll
    for (int dh = 0; dh < 3; ++dh)
#pragma unroll
        for (int dw = 0; dw < 3; ++dw) {
            float wv = w[(dh * 3 + dw) * 256 + c];
            acc[0][0] += pin[dh][dw] * wv;
            acc[0][1] += pin[dh][dw + 1] * wv;
            acc[1][0] += pin[dh + 1][dw] * wv;
            acc[1][1] += pin[dh + 1][dw + 1] * wv;
        }
    float m = fmaxf(fmaxf(acc[0][0], acc[0][1]), fmaxf(acc[1][0], acc[1][1]));
    out[(ph * 255 + pw) * 256 + c] = fmaxf(m + b[c], 0.f);
}

// ---------------- STFT conv2 (3x3x256->256) + relu + 2x2 maxpool ----------------
__global__ void stft_conv2_kernel(const float* __restrict__ P1, const float* __restrict__ w,
                                  const float* __restrict__ b, float* __restrict__ out) {
    __shared__ float patch[4 * 8 * 256];
    int c = threadIdx.x;
    int blk = blockIdx.x;
    int pwg = blk % 42, ph = blk / 42;
    int pw0 = pwg * 3;
    int r0 = 2 * ph, c0 = 2 * pw0;
    for (int i = c; i < 4 * 8 * 256; i += 256) {
        int ci = i & 255;
        int t = i >> 8;
        int cc = t & 7, r = t >> 3;
        patch[i] = P1[((r0 + r) * 255 + (c0 + cc)) * 256 + ci];
    }
    __syncthreads();
    float acc[3][2][2] = {};
    for (int dh = 0; dh < 3; ++dh) {
        for (int ci = 0; ci < 256; ++ci) {
            float p0[8], p1[8];
#pragma unroll
            for (int x = 0; x < 8; ++x) {
                p0[x] = patch[(dh * 8 + x) * 256 + ci];
                p1[x] = patch[((dh + 1) * 8 + x) * 256 + ci];
            }
#pragma unroll
            for (int dw = 0; dw < 3; ++dw) {
                float wv = w[((dh * 3 + dw) * 256 + ci) * 256 + c];
#pragma unroll
                for (int o = 0; o < 3; ++o)
#pragma unroll
                    for (int s = 0; s < 2; ++s) {
                        acc[o][0][s] += p0[2 * o + s + dw] * wv;
                        acc[o][1][s] += p1[2 * o + s + dw] * wv;
                    }
            }
        }
    }
    float bv = b[c];
#pragma unroll
    for (int o = 0; o < 3; ++o) {
        float m = fmaxf(fmaxf(acc[o][0][0], acc[o][0][1]), fmaxf(acc[o][1][0], acc[o][1][1]));
        out[(ph * 126 + (pw0 + o)) * 256 + c] = fmaxf(m + bv, 0.f);
    }
}

// ---------------- STFT input projection: X[14,32256] @ Wi[32256,1024], split-K ----------------
__global__ void xprojS_partial_kernel(const float* __restrict__ X, const float* __restrict__ Wi,
                                      float* __restrict__ part) {
    __shared__ float xbuf[14 * 504];
    int tid = threadIdx.x;
    int kc = blockIdx.x & 63;
    int cb = blockIdx.x >> 6;
    int col = cb * 256 + tid;
    int k0 = kc * 504;
    for (int i = tid; i < 14 * 504; i += 256) {
        int t = i / 504;
        int kk = i - t * 504;
        xbuf[i] = X[t * 32256 + k0 + kk];
    }
    __syncthreads();
    float acc[14] = {};
    for (int kk = 0; kk < 504; ++kk) {
        float wv = Wi[(size_t)(k0 + kk) * 1024 + col];
#pragma unroll
        for (int t = 0; t < 14; ++t) acc[t] += xbuf[t * 504 + kk] * wv;
    }
#pragma unroll
    for (int t = 0; t < 14; ++t) part[(kc * 14 + t) * 1024 + col] = acc[t];
}

__global__ void xprojS_reduce_kernel(const float* __restrict__ part, const float* __restrict__ bias,
                                     float* __restrict__ xp) {
    int idx = blockIdx.x * 256 + threadIdx.x;  // < 14*1024
    int t = idx >> 10, col = idx & 1023;
    float s = bias[col];
    for (int kc = 0; kc < 64; ++kc) s += part[(kc * 14 + t) * 1024 + col];
    xp[idx] = s;
}

// ---------------- wave conv1 (k=3, 1024->256) + relu + pool2 ----------------
__global__ void wave_conv1_kernel(const float* __restrict__ in, const float* __restrict__ w,
                                  const float* __restrict__ b, float* __restrict__ out) {
    __shared__ float patch[4 * 1024];
    int c = threadIdx.x, t = blockIdx.x;
    for (int i = c; i < 4 * 1024; i += 256) patch[i] = in[(2 * t) * 1024 + i];
    __syncthreads();
    float acc0 = 0.f, acc1 = 0.f;
    for (int dt = 0; dt < 3; ++dt)
        for (int ci = 0; ci < 1024; ++ci) {
            float wv = w[(dt * 1024 + ci) * 256 + c];
            acc0 += patch[dt * 1024 + ci] * wv;
            acc1 += patch[(dt + 1) * 1024 + ci] * wv;
        }
    out[t * 256 + c] = fmaxf(fmaxf(acc0, acc1) + b[c], 0.f);
}

// ---------------- wave conv2 (k=3, 256->256) + relu + pool2 ----------------
__global__ void wave_conv2_kernel(const float* __restrict__ in, const float* __restrict__ w,
                                  const float* __restrict__ b, float* __restrict__ out) {
    __shared__ float patch[4 * 256];
    int c = threadIdx.x, t = blockIdx.x;
    for (int i = c; i < 4 * 256; i += 256) patch[i] = in[(2 * t) * 256 + i];
    __syncthreads();
    float acc0 = 0.f, acc1 = 0.f;
    for (int dt = 0; dt < 3; ++dt)
        for (int ci = 0; ci < 256; ++ci) {
            float wv = w[(dt * 256 + ci) * 256 + c];
            acc0 += patch[dt * 256 + ci] * wv;
            acc1 += patch[(dt + 1) * 256 + ci] * wv;
        }
    out[t * 256 + c] = fmaxf(fmaxf(acc0, acc1) + b[c], 0.f);
}

// ---------------- wave input projection X[62,256] @ Wi[256,1024] + b ----------------
__global__ void xprojW_kernel(const float* __restrict__ X, const float* __restrict__ Wi,
                              const float* __restrict__ bias, float* __restrict__ xp) {
    int idx = blockIdx.x * 256 + threadIdx.x;  // 62*1024
    int t = idx >> 10, col = idx & 1023;
    float s = bias[col];
    for (int k = 0; k < 256; ++k) s += X[t * 256 + k] * Wi[k * 1024 + col];
    xp[idx] = s;
}

// ---------------- state reducers ----------------
__global__ void reduce_state_kernel(const float* __restrict__ sh, const float* __restrict__ sc,
                                    const float* __restrict__ wh, const float* __restrict__ wc,
                                    const float* __restrict__ rhw, const float* __restrict__ rhb,
                                    const float* __restrict__ rcw, const float* __restrict__ rcb,
                                    float* __restrict__ h0, float* __restrict__ c0) {
    int m = threadIdx.x;  // 256
    float ah = rhb[m], ac = rcb[m];
    for (int k = 0; k < 256; ++k) {
        ah += sh[k] * rhw[k * 256 + m];
        ac += sc[k] * rcw[k * 256 + m];
    }
    for (int k = 0; k < 256; ++k) {
        ah += wh[k] * rhw[(256 + k) * 256 + m];
        ac += wc[k] * rcw[(256 + k) * 256 + m];
    }
    h0[m] = ah;
    c0[m] = ac;
}

// ---------------- a0/a1 = emb[s] @ d_Wi + d_b ----------------
__global__ void a01_kernel(const float* __restrict__ emb, const float* __restrict__ Wi,
                           const float* __restrict__ bias, float* __restrict__ a01) {
    int idx = blockIdx.x * 256 + threadIdx.x;  // 2048
    int s = idx >> 10, j = idx & 1023;
    float acc = bias[j];
    for (int k = 0; k < 256; ++k) acc += emb[s * 256 + k] * Wi[k * 1024 + j];
    a01[idx] = acc;
}

// ---------------- projection + softmax epilogue: 4 rows/block, 256 threads ----------------
__global__ __launch_bounds__(256) void proj_softmax_kernel(const __hip_bfloat16* __restrict__ hh,
                                                           const float* __restrict__ Wo,
                                                           const float* __restrict__ bo,
                                                           float* __restrict__ out) {
    __shared__ float hrows[4][256];
    __shared__ float llds[4][128];
    int tid = threadIdx.x;
    int rbase = blockIdx.x * 4;
    for (int i = tid; i < 1024; i += 256)
        hrows[i >> 8][i & 255] = __bfloat162float(hh[(size_t)rbase * 256 + i]);
    __syncthreads();
    int w = tid & 127, half = tid >> 7;
    int k0 = half * 128;
    float acc[4] = {};
    for (int k = 0; k < 128; ++k) {
        float wv = Wo[(k0 + k) * 128 + w];
#pragma unroll
        for (int r = 0; r < 4; ++r) acc[r] += hrows[r][k0 + k] * wv;
    }
    if (half == 0) {
#pragma unroll
        for (int r = 0; r < 4; ++r) llds[r][w] = acc[r] + bo[w];
    }
    __syncthreads();
    if (half == 1) {
#pragma unroll
        for (int r = 0; r < 4; ++r) llds[r][w] += acc[r];
    }
    __syncthreads();
    int rr = tid >> 6, lane = tid & 63;
    float x0 = llds[rr][lane], x1 = llds[rr][lane + 64];
    float mx = fmaxf(x0, x1);
    for (int off = 32; off > 0; off >>= 1) mx = fmaxf(mx, __shfl_xor(mx, off));
    float e0 = __expf(x0 - mx), e1 = __expf(x1 - mx);
    float sm = e0 + e1;
    for (int off = 32; off > 0; off >>= 1) sm += __shfl_xor(sm, off);
    float inv = 1.f / sm;
    int row = rbase + rr;
    int l = row >> 7, v = row & 127;
    float* op = out + ((size_t)v * 300 + l) * 128;
    op[lane] = e0 * inv;
    op[lane + 64] = e1 * inv;
}

// ---------------- zero last time slot l=299 ----------------
__global__ void zero_tail_kernel(float* __restrict__ out) {
    int idx = blockIdx.x * 256 + threadIdx.x;  // 128*128
    int v = idx >> 7, w = idx & 127;
    out[((size_t)v * 300 + 299) * 128 + w] = 0.f;
}

extern "C" void kernel_launch(void* const* d_in, const int* in_sizes, int n_in, void* d_out,
                              int out_size, void* d_ws, size_t ws_size, hipStream_t stream) {
    const float* stft = (const float*)d_in[0];
    const float* wave = (const float*)d_in[1];
    const float* din = (const float*)d_in[2];
    const float* s_cw1 = (const float*)d_in[3];
    const float* s_cb1 = (const float*)d_in[4];
    const float* s_cw2 = (const float*)d_in[5];
    const float* s_cb2 = (const float*)d_in[6];
    const float* s_Wi = (const float*)d_in[7];
    const float* s_Wh = (const float*)d_in[8];
    const float* s_b = (const float*)d_in[9];
    const float* w_cw1 = (const float*)d_in[10];
    const float* w_cb1 = (const float*)d_in[11];
    const float* w_cw2 = (const float*)d_in[12];
    const float* w_cb2 = (const float*)d_in[13];
    const float* w_Wi = (const float*)d_in[14];
    const float* w_Wh = (const float*)d_in[15];
    const float* w_b = (const float*)d_in[16];
    const float* rh_w = (const float*)d_in[17];
    const float* rh_b = (const float*)d_in[18];
    const float* rc_w = (const float*)d_in[19];
    const float* rc_b = (const float*)d_in[20];
    const float* emb = (const float*)d_in[21];
    const float* d_Wi = (const float*)d_in[22];
    const float* d_Wh = (const float*)d_in[23];
    const float* d_b = (const float*)d_in[24];
    const float* out_w = (const float*)d_in[25];
    const float* out_b = (const float*)d_in[26];
    float* out = (float*)d_out;
    float* ws = (float*)d_ws;

    // workspace layout (float offsets)
    const size_t off_P1s = 0;                         // 31*255*256 = 2023680 (reused for packed weights)
    const size_t off_P2s = off_P1s + 2023680;         // 14*126*256 = 451584
    const size_t off_partS = off_P2s + 451584;        // 64*14*1024 = 917504
    const size_t off_P1w = off_partS + 917504;        // 127*256 = 32512
    const size_t off_P2w = off_P1w + 32512;           // 62*256 = 15872
    const size_t off_xprojS = off_P2w + 15872;        // 14*1024
    const size_t off_xprojW = off_xprojS + 14336;     // 62*1024
    const size_t off_sh = off_xprojW + 63488;         // 4*256 states
    const size_t off_sc = off_sh + 256;
    const size_t off_wh = off_sc + 256;
    const size_t off_wc = off_wh + 256;
    const size_t off_h0 = off_wc + 256;
    const size_t off_c0 = off_h0 + 256;
    const size_t off_a01 = off_c0 + 256;              // 2048
    const size_t off_tok = off_a01 + 2048;            // 299 ints (512 slots)
    const size_t off_hh = off_tok + 512;              // bf16 region: 38272*256 bf16
    __hip_bfloat16* h_hist = (__hip_bfloat16*)(ws + off_hh);
    int* tok = (int*)(ws + off_tok);
    // packed f16 weights overlay the P1s region (free after stft_conv2): 3 x 131072 dwords
    uint32_t* wrS = (uint32_t*)(ws + off_P1s);
    uint32_t* wrW = wrS + 131072;
    uint32_t* wrD = wrW + 131072;

    tok_kernel<<<5, 64, 0, stream>>>(din, tok);

    // STFT conv pipeline (P1s in use until stft_conv2 completes)
    stft_conv1_kernel<<<31 * 255, 256, 0, stream>>>(stft, s_cw1, s_cb1, ws + off_P1s);
    stft_conv2_kernel<<<14 * 42, 256, 0, stream>>>(ws + off_P1s, s_cw2, s_cb2, ws + off_P2s);

    // repack all three Wh matrices into f16x2 layout (P1s region now free)
    prep_wh_kernel<<<512, 256, 0, stream>>>(s_Wh, wrS);
    prep_wh_kernel<<<512, 256, 0, stream>>>(w_Wh, wrW);
    prep_wh_kernel<<<512, 256, 0, stream>>>(d_Wh, wrD);

    xprojS_partial_kernel<<<256, 256, 0, stream>>>(ws + off_P2s, s_Wi, ws + off_partS);
    xprojS_reduce_kernel<<<56, 256, 0, stream>>>(ws + off_partS, s_b, ws + off_xprojS);
    lstm_enc3_kernel<<<1, 512, 0, stream>>>(wrS, ws + off_xprojS, 14, ws + off_sh, ws + off_sc);

    // waveform branch
    wave_conv1_kernel<<<127, 256, 0, stream>>>(wave, w_cw1, w_cb1, ws + off_P1w);
    wave_conv2_kernel<<<62, 256, 0, stream>>>(ws + off_P1w, w_cw2, w_cb2, ws + off_P2w);
    xprojW_kernel<<<248, 256, 0, stream>>>(ws + off_P2w, w_Wi, w_b, ws + off_xprojW);
    lstm_enc3_kernel<<<1, 512, 0, stream>>>(wrW, ws + off_xprojW, 62, ws + off_wh, ws + off_wc);

    // reducers + decoder precompute
    reduce_state_kernel<<<1, 256, 0, stream>>>(ws + off_sh, ws + off_sc, ws + off_wh, ws + off_wc,
                                               rh_w, rh_b, rc_w, rc_b, ws + off_h0, ws + off_c0);
    a01_kernel<<<8, 256, 0, stream>>>(emb, d_Wi, d_b, ws + off_a01);

    // sequential decoder chain (critical path)
    lstm_dec4_kernel<<<1, 512, 0, stream>>>(wrD, ws + off_a01, tok, ws + off_h0, ws + off_c0,
                                            h_hist);

    // parallel epilogue
    proj_softmax_kernel<<<NSTEP / 4, 256, 0, stream>>>(h_hist, out_w, out_b, out);
    zero_tail_kernel<<<64, 256, 0, stream>>>(out);
}